// Round 12
// baseline (515.296 us; speedup 1.0000x reference)
//
#include <hip/hip_runtime.h>
#include <math.h>

typedef unsigned short ushort_t;
typedef __bf16 bf16x8 __attribute__((ext_vector_type(8)));
typedef float f32x4 __attribute__((ext_vector_type(4)));

#define NBLK 512
#define POISON 0xAAAAAAAAu

// ---------------------------------------------------------------------------
// fp32 <-> bf16 helpers
// ---------------------------------------------------------------------------
__device__ __forceinline__ ushort_t f2b_rne(float f) {
    union { float f; unsigned int u; } c;
    c.f = f;
    unsigned int u = c.u;
    u += 0x7FFFu + ((u >> 16) & 1u);
    return (ushort_t)(u >> 16);
}
__device__ __forceinline__ float b2f(ushort_t v) {
    union { unsigned int u; float f; } c;
    c.u = ((unsigned int)v) << 16;
    return c.f;
}

// async global->LDS DMA, 16B per lane.
__device__ __forceinline__ void gl_lds16(const ushort_t* g, ushort_t* l) {
    __builtin_amdgcn_global_load_lds(
        (const __attribute__((address_space(1))) void*)g,
        (__attribute__((address_space(3))) void*)l, 16, 0, 0);
}

// Grid barrier, split arrive/wait. Counters start at POISON (harness
// poisons d_ws with 0xAA before every launch). Arrival = one RMW (release);
// polling = atomic LOAD (acquire, agent scope) — concurrent same-line loads
// don't serialize like RMWs (round-11 lesson: RMW-polling poisoned the L2).
__device__ __forceinline__ void bar_arrive(unsigned* c) {
    __syncthreads();
    if (threadIdx.x == 0) {
        __threadfence();  // release this block's phase writes
        __hip_atomic_fetch_add(c, 1u, __ATOMIC_RELEASE, __HIP_MEMORY_SCOPE_AGENT);
    }
}
__device__ __forceinline__ void bar_wait(unsigned* c) {
    if (threadIdx.x == 0) {
        while ((__hip_atomic_load(c, __ATOMIC_ACQUIRE, __HIP_MEMORY_SCOPE_AGENT)
                - POISON) < NBLK)
            __builtin_amdgcn_s_sleep(8);
    }
    __syncthreads();
}

// ---------------------------------------------------------------------------
// mega: all 5 phases in one persistent kernel, 512 blocks x 256 thr.
// Blocks with no work in later phases arrive-and-exit (few spinners).
// ---------------------------------------------------------------------------
__global__ __launch_bounds__(256, 2) void mega(
    const float* __restrict__ x, const float* __restrict__ context,
    const float* __restrict__ Wq, const float* __restrict__ Wk,
    const float* __restrict__ Wv1, const float* __restrict__ ln_g,
    const float* __restrict__ ln_b, const float* __restrict__ Wc,
    const float* __restrict__ Wout,
    unsigned* __restrict__ cnt,
    float* __restrict__ S, float* __restrict__ colsum,
    float* __restrict__ colsumsq,
    ushort_t* __restrict__ x_b, ushort_t* __restrict__ ctx_b,
    ushort_t* __restrict__ qb, ushort_t* __restrict__ kb,
    ushort_t* __restrict__ h1t,
    ushort_t* __restrict__ Wq_t, ushort_t* __restrict__ Wk_t,
    ushort_t* __restrict__ Wv1_t, ushort_t* __restrict__ Wout_t,
    ushort_t* __restrict__ outp_b, float* __restrict__ out,
    int b, int n) {
    __shared__ __align__(16) unsigned char smem[54512];

    const int bid = blockIdx.x;
    const int t = threadIdx.x;
    const int M = b * 64;
    const int Mn = b * n;
    const int lane = t & 63;
    const int wave = t >> 6;
    const int quad = lane >> 4;
    const int l15 = lane & 15;

    // ============== PHASE A: conversions + zero LN accumulators ==============
    {
        const int nb_x = (M * 768 / 4) / 256;
        const int nb_c = (Mn * 768 / 4) / 256;
        const int nvA = nb_x + nb_c + 4800 + 8;
        float (*tt)[33] = (float(*)[33])smem;

        for (int vb = bid; vb < nvA; vb += NBLK) {
            if (vb < nb_x + nb_c) {  // flat converts
                const float* in = (vb < nb_x) ? x : context;
                ushort_t* outp = (vb < nb_x) ? x_b : ctx_b;
                const int i = ((vb < nb_x) ? vb : (vb - nb_x)) * 256 + t;
                float4 v = ((const float4*)in)[i];
                ushort_t o[4] = {f2b_rne(v.x), f2b_rne(v.y), f2b_rne(v.z), f2b_rne(v.w)};
                *(uint2*)&outp[(size_t)i * 4] = *(uint2*)o;
                continue;
            }
            int u = vb - nb_x - nb_c;
            if (u >= 4800) {  // zero colsum|colsumsq (contiguous 2*Mn floats)
                const int idx = (u - 4800) * 256 + t;
                ((float4*)colsum)[idx] = make_float4(0.f, 0.f, 0.f, 0.f);
                continue;
            }
            // transposes: Wq 576, Wk 576, Wv1 3072, Wout 576
            const float* in;
            ushort_t* outp;
            int R = 768, C = 768;
            if (u < 576)        { in = Wq;  outp = Wq_t; }
            else if (u < 1152)  { u -= 576;  in = Wk;  outp = Wk_t; }
            else if (u < 4224)  { u -= 1152; in = Wv1; outp = Wv1_t; C = 4096; }
            else                { u -= 4224; in = Wout; outp = Wout_t; }
            const int ct = C / 32;
            const int c0 = (u % ct) * 32, r0 = (u / ct) * 32;
            const int tx = t & 31, ty = t >> 5;
#pragma unroll
            for (int i = 0; i < 4; i++)
                tt[ty + 8 * i][tx] = in[(size_t)(r0 + ty + 8 * i) * C + c0 + tx];
            __syncthreads();
#pragma unroll
            for (int i = 0; i < 4; i++)
                outp[(size_t)(c0 + ty + 8 * i) * R + r0 + tx] =
                    f2b_rne(tt[tx][ty + 8 * i]);
            __syncthreads();
        }
    }
    bar_arrive(&cnt[0]);
    bar_wait(&cnt[0]);

    // ============== PHASE B: q, k, h1^T GEMMs (m97 staging) ==============
    {
        const int tq = (M / 128) * 6;
        const int tk = (Mn / 128) * 6;
        const int th = 32 * (Mn / 128);
        ushort_t* As = (ushort_t*)smem;          // 128*32
        ushort_t* Bs = As + 128 * 32;
        const int wm = (wave >> 1) * 64;
        const int wn = (wave & 1) * 64;
        const int K = 768;

        for (int vb = bid; vb < tq + tk + th; vb += NBLK) {
            const ushort_t *A, *Bt;
            ushort_t* C;
            int N, row0, col0;
            if (vb < tq) {
                A = x_b; Bt = Wq_t; C = qb; N = 768;
                row0 = (vb / 6) * 128; col0 = (vb % 6) * 128;
            } else if (vb < tq + tk) {
                const int u = vb - tq;
                A = ctx_b; Bt = Wk_t; C = kb; N = 768;
                row0 = (u / 6) * 128; col0 = (u % 6) * 128;
            } else {
                const int u = vb - tq - tk;
                A = Wv1_t; Bt = ctx_b; C = h1t; N = Mn;
                row0 = (u % 32) * 128; col0 = (u / 32) * 128;
            }
            const ushort_t* ga0 = A + (size_t)(row0 + (t >> 2)) * K + (t & 3) * 8;
            const ushort_t* ga1 = ga0 + (size_t)64 * K;
            const ushort_t* gb0 = Bt + (size_t)(col0 + (t >> 2)) * K + (t & 3) * 8;
            const ushort_t* gb1 = gb0 + (size_t)64 * K;
            ushort_t* lA0 = &As[wave * 512];
            ushort_t* lA1 = &As[2048 + wave * 512];
            ushort_t* lB0 = &Bs[wave * 512];
            ushort_t* lB1 = &Bs[2048 + wave * 512];

            f32x4 acc[4][4] = {};
            for (int k0 = 0; k0 < K; k0 += 32) {
                __syncthreads();
                gl_lds16(ga0 + k0, lA0);
                gl_lds16(ga1 + k0, lA1);
                gl_lds16(gb0 + k0, lB0);
                gl_lds16(gb1 + k0, lB1);
                __syncthreads();
                bf16x8 af[4], bfr[4];
#pragma unroll
                for (int i = 0; i < 4; i++)
                    af[i] = *(const bf16x8*)&As[(wm + i * 16 + l15) * 32 + quad * 8];
#pragma unroll
                for (int j = 0; j < 4; j++)
                    bfr[j] = *(const bf16x8*)&Bs[(wn + j * 16 + l15) * 32 + quad * 8];
#pragma unroll
                for (int i = 0; i < 4; i++)
#pragma unroll
                    for (int j = 0; j < 4; j++)
                        acc[i][j] = __builtin_amdgcn_mfma_f32_16x16x32_bf16(
                            af[i], bfr[j], acc[i][j], 0, 0, 0);
            }
#pragma unroll
            for (int i = 0; i < 4; i++)
#pragma unroll
                for (int j = 0; j < 4; j++)
#pragma unroll
                    for (int r = 0; r < 4; r++) {
                        const int row = row0 + wm + i * 16 + quad * 4 + r;
                        const int col = col0 + wn + j * 16 + l15;
                        C[(size_t)row * N + col] = f2b_rne(acc[i][j][r]);
                    }
            __syncthreads();  // protect As/Bs for next vtile
        }
    }
    bar_arrive(&cnt[1]);
    bar_wait(&cnt[1]);

    // ============== PHASE C: scores + LN column sums ==============
    {
        const int nsc = b * 8 * (n / 128);
        const int nvC = nsc + 256;
        ushort_t* sb = (ushort_t*)smem;  // 192*104 (39936 B)

        for (int vb = bid; vb < nvC; vb += NBLK) {
            if (vb >= nsc) {  // LN column-sum panel (256 rows x 256 cols)
                const int u = vb - nsc;
                const int rc = u >> 4;
                const int cc = u & 15;
                const int cg = t & 31;
                const int rg = t >> 5;
                const ushort_t* p =
                    h1t + (size_t)(rc * 256 + rg * 32) * Mn + cc * 256 + cg * 8;
                float s[8] = {}, s2[8] = {};
#pragma unroll 4
                for (int r = 0; r < 32; r++) {
                    const bf16x8 v = *(const bf16x8*)&p[(size_t)r * Mn];
#pragma unroll
                    for (int j = 0; j < 8; j++) {
                        const float f = (float)v[j];
                        s[j] += f;
                        s2[j] += f * f;
                    }
                }
                float* red = (float*)sb;
#pragma unroll
                for (int j = 0; j < 8; j++) {
                    red[rg * 256 + cg * 8 + j] = s[j];
                    red[2048 + rg * 256 + cg * 8 + j] = s2[j];
                }
                __syncthreads();
                float ts = 0.f, ts2 = 0.f;
#pragma unroll
                for (int g = 0; g < 8; g++) {
                    ts += red[g * 256 + t];
                    ts2 += red[2048 + g * 256 + t];
                }
                atomicAdd(&colsum[cc * 256 + t], ts);
                atomicAdd(&colsumsq[cc * 256 + t], ts2);
                __syncthreads();
                continue;
            }
            // scores tile
            const int nt = n / 128;
            const int n0 = (vb % nt) * 128;
            const int bh = vb / nt;
            const int bb = bh >> 3, h = bh & 7;
            const int wm = (wave >> 1) * 32;
            const int wn = (wave & 1) * 64;
            ushort_t* Qs = sb;
            ushort_t* Ks = sb + 64 * 104;

            for (int g = t; g < 768; g += 256) {
                const int r = g / 12, s = g - r * 12;
                *(bf16x8*)&Qs[r * 104 + s * 8] =
                    *(const bf16x8*)&qb[(size_t)(bb * 64 + r) * 768 + h * 96 + s * 8];
            }
            for (int g = t; g < 1536; g += 256) {
                const int r = g / 12, s = g - r * 12;
                *(bf16x8*)&Ks[r * 104 + s * 8] =
                    *(const bf16x8*)&kb[(size_t)(bb * n + n0 + r) * 768 + h * 96 + s * 8];
            }
            __syncthreads();

            f32x4 acc[2][4] = {};
#pragma unroll
            for (int ks = 0; ks < 3; ks++) {
                bf16x8 af[2], bfr[4];
#pragma unroll
                for (int i = 0; i < 2; i++)
                    af[i] = *(const bf16x8*)&Qs[(wm + i * 16 + l15) * 104 + ks * 32 + quad * 8];
#pragma unroll
                for (int j = 0; j < 4; j++)
                    bfr[j] = *(const bf16x8*)&Ks[(wn + j * 16 + l15) * 104 + ks * 32 + quad * 8];
#pragma unroll
                for (int i = 0; i < 2; i++)
#pragma unroll
                    for (int j = 0; j < 4; j++)
                        acc[i][j] = __builtin_amdgcn_mfma_f32_16x16x32_bf16(
                            af[i], bfr[j], acc[i][j], 0, 0, 0);
            }
            const float sc = 0.10206207261596575f;  // 1/sqrt(96)
            float* Sp = S + (size_t)bh * 64 * n;
#pragma unroll
            for (int i = 0; i < 2; i++)
#pragma unroll
                for (int j = 0; j < 4; j++)
#pragma unroll
                    for (int r = 0; r < 4; r++) {
                        const int row = wm + i * 16 + quad * 4 + r;
                        const int col = n0 + wn + j * 16 + l15;
                        Sp[(size_t)row * n + col] = acc[i][j][r] * sc;
                    }
            __syncthreads();
        }
    }
    bar_arrive(&cnt[2]);

    // Blocks with no phase-D work: arrive at cnt[3] too (no new writes since
    // cnt[2] arrival) and exit — they never spin.
    if (bid >= M) {
        bar_arrive(&cnt[3]);
        return;
    }
    bar_wait(&cnt[2]);

    // ============== PHASE D: fused softmax + PV-MFMA + LN + Wc ==============
    {
        const int bq = bid;
        const int bb = bq >> 6, qi = bq & 63;
        ushort_t* sW = (ushort_t*)smem;                 // 9*1032
        ushort_t* sH = sW + 9 * 1032;                   // 64*264
        float* sA = (float*)(smem + 52368);             // 512
        float* sm = (float*)(smem + 54416);             // 8
        float* sl = sm + 8;
        float* swmu = sl + 8;
        float* sMu = (float*)sH;                        // overlay, dead after use
        float* sRs = (float*)sH + 1024;

        for (int i = t; i < n; i += 256) {
            const float cs = colsum[bb * n + i];
            const float cq = colsumsq[bb * n + i];
            const float m = cs * (1.0f / 4096.0f);
            sMu[i] = m;
            sRs[i] = rsqrtf(cq * (1.0f / 4096.0f) - m * m + 1e-5f);
        }
        for (int i = t; i < 1032; i += 256) sW[8 * 1032 + i] = 0;
        __syncthreads();

#pragma unroll
        for (int s = 0; s < 2; s++) {
            const int h = wave * 2 + s;
            const float* Sp = S + ((size_t)(bb * 8 + h) * 64 + qi) * n;
            float m = -1e30f;
            for (int i = lane; i < n; i += 64) m = fmaxf(m, Sp[i]);
#pragma unroll
            for (int off = 32; off > 0; off >>= 1) m = fmaxf(m, __shfl_down(m, off));
            m = __shfl(m, 0);
            float l = 0.f, wm = 0.f;
            for (int i = lane; i < n; i += 64) {
                const float e = expf(Sp[i] - m);
                const float w = e * sRs[i];
                const ushort_t wb = f2b_rne(w);
                sW[h * 1032 + i] = wb;
                l += e;
                wm += b2f(wb) * sMu[i];
            }
#pragma unroll
            for (int off = 32; off > 0; off >>= 1) {
                l += __shfl_down(l, off);
                wm += __shfl_down(wm, off);
            }
            if (lane == 0) { sm[h] = m; sl[h] = l; swmu[h] = wm; }
        }

        const int mrow = (l15 < 8 ? l15 : 8) * 1032;
        f32x4 acc[4] = {};
        const int nch = n >> 8;
        for (int ch = 0; ch < nch; ch++) {
            __syncthreads();
            for (int g = t; g < 2048; g += 256) {
                const int row = g >> 5, seg = g & 31;
                *(bf16x8*)&sH[row * 264 + seg * 8] =
                    *(const bf16x8*)&h1t[(size_t)(qi * 64 + row) * Mn + bb * n +
                                         ch * 256 + seg * 8];
            }
            __syncthreads();
#pragma unroll
            for (int ks = 0; ks < 8; ks++) {
                const bf16x8 af = *(const bf16x8*)&sW[mrow + ch * 256 + ks * 32 + quad * 8];
#pragma unroll
                for (int j = 0; j < 4; j++) {
                    const bf16x8 bf = *(const bf16x8*)&sH[(j * 16 + l15) * 264 + ks * 32 + quad * 8];
                    acc[j] = __builtin_amdgcn_mfma_f32_16x16x32_bf16(af, bf, acc[j], 0, 0, 0);
                }
            }
        }
        __syncthreads();

        if (wave == 0) {
#pragma unroll
            for (int j = 0; j < 4; j++)
#pragma unroll
                for (int r = 0; r < 4; r++) {
                    const int h = quad * 4 + r;
                    if (h < 8) {
                        const int rr = j * 16 + l15;
                        const int c = qi * 64 + rr;
                        sA[h * 64 + rr] =
                            ln_g[c] * ((acc[j][r] - swmu[h]) / sl[h]) + ln_b[c];
                    }
                }
        }
        __syncthreads();

        for (int d = t; d < 768; d += 256) {
            const int h = d / 96;
            const float* wp = Wc + (size_t)qi * 49152 + d;
            float a = 0.f;
#pragma unroll
            for (int r = 0; r < 64; r++) a += sA[h * 64 + r] * wp[(size_t)r * 768];
            outp_b[(size_t)bq * 768 + d] = f2b_rne(a);
        }
    }
    bar_arrive(&cnt[3]);

    // Only the 12 phase-E blocks spin on cnt[3]; everyone else exits.
    if (bid >= (M / 128) * 6) return;
    bar_wait(&cnt[3]);

    // ============== PHASE E: out = outp_b @ Wout_t^T (fp32) ==============
    {
        ushort_t* As = (ushort_t*)smem;       // 128*40
        ushort_t* Bs = As + 128 * 40;
        const int row0 = (bid / 6) * 128, col0 = (bid % 6) * 128;
        const int wm = (wave >> 1) * 64;
        const int wn = (wave & 1) * 64;
        const int K = 768, N = 768;
        const int srow = t >> 2, sseg = t & 3;
        const ushort_t* ga0 = outp_b + (size_t)(row0 + srow) * K + sseg * 8;
        const ushort_t* ga1 = outp_b + (size_t)(row0 + srow + 64) * K + sseg * 8;
        const ushort_t* gb0 = Wout_t + (size_t)(col0 + srow) * K + sseg * 8;
        const ushort_t* gb1 = Wout_t + (size_t)(col0 + srow + 64) * K + sseg * 8;

        f32x4 acc[4][4] = {};
        bf16x8 ra0 = *(const bf16x8*)ga0;
        bf16x8 ra1 = *(const bf16x8*)ga1;
        bf16x8 rb0 = *(const bf16x8*)gb0;
        bf16x8 rb1 = *(const bf16x8*)gb1;

        for (int k0 = 0; k0 < K; k0 += 32) {
            __syncthreads();
            *(bf16x8*)&As[srow * 40 + sseg * 8] = ra0;
            *(bf16x8*)&As[(srow + 64) * 40 + sseg * 8] = ra1;
            *(bf16x8*)&Bs[srow * 40 + sseg * 8] = rb0;
            *(bf16x8*)&Bs[(srow + 64) * 40 + sseg * 8] = rb1;
            __syncthreads();
            if (k0 + 32 < K) {
                ra0 = *(const bf16x8*)(ga0 + k0 + 32);
                ra1 = *(const bf16x8*)(ga1 + k0 + 32);
                rb0 = *(const bf16x8*)(gb0 + k0 + 32);
                rb1 = *(const bf16x8*)(gb1 + k0 + 32);
            }
            bf16x8 af[4], bfr[4];
#pragma unroll
            for (int i = 0; i < 4; i++)
                af[i] = *(const bf16x8*)&As[(wm + i * 16 + l15) * 40 + quad * 8];
#pragma unroll
            for (int j = 0; j < 4; j++)
                bfr[j] = *(const bf16x8*)&Bs[(wn + j * 16 + l15) * 40 + quad * 8];
#pragma unroll
            for (int i = 0; i < 4; i++)
#pragma unroll
                for (int j = 0; j < 4; j++)
                    acc[i][j] = __builtin_amdgcn_mfma_f32_16x16x32_bf16(
                        af[i], bfr[j], acc[i][j], 0, 0, 0);
        }
#pragma unroll
        for (int i = 0; i < 4; i++)
#pragma unroll
            for (int j = 0; j < 4; j++)
#pragma unroll
                for (int r = 0; r < 4; r++) {
                    const int row = row0 + wm + i * 16 + quad * 4 + r;
                    const int col = col0 + wn + j * 16 + l15;
                    out[(size_t)row * N + col] = acc[i][j][r];
                }
    }
}

// ---------------------------------------------------------------------------
extern "C" void kernel_launch(void* const* d_in, const int* in_sizes, int n_in,
                              void* d_out, int out_size, void* d_ws, size_t ws_size,
                              hipStream_t stream) {
    const float* x       = (const float*)d_in[0];
    const float* context = (const float*)d_in[1];
    const float* Wq      = (const float*)d_in[2];
    const float* Wk      = (const float*)d_in[3];
    const float* Wv1     = (const float*)d_in[4];
    const float* ln_g    = (const float*)d_in[5];
    const float* ln_b    = (const float*)d_in[6];
    const float* Wc      = (const float*)d_in[7];
    const float* Wout    = (const float*)d_in[8];
    float* out = (float*)d_out;

    const int b = in_sizes[0] / (64 * 768);
    const int n = in_sizes[1] / (b * 768);
    const int M  = b * 64;     // 256
    const int Mn = b * n;      // 4096

    unsigned* cnt = (unsigned*)d_ws;            // 64 u32 (256 B), poison-init
    float* ws = (float*)d_ws + 64;
    size_t off = 0;
    float* S       = ws + off;  off += (size_t)b * 8 * 64 * n;
    float* colsum  = ws + off;  off += (size_t)Mn;
    float* colsumsq= ws + off;  off += (size_t)Mn;

    ushort_t* us = (ushort_t*)(ws + off);
    size_t uo = 0;
    ushort_t* x_b    = us + uo;  uo += (size_t)M * 768;
    ushort_t* ctx_b  = us + uo;  uo += (size_t)Mn * 768;
    ushort_t* qb     = us + uo;  uo += (size_t)M * 768;
    ushort_t* kb     = us + uo;  uo += (size_t)Mn * 768;
    ushort_t* h1t    = us + uo;  uo += (size_t)Mn * 4096;   // [c][n_glob]
    ushort_t* Wq_t   = us + uo;  uo += (size_t)768 * 768;
    ushort_t* Wk_t   = us + uo;  uo += (size_t)768 * 768;
    ushort_t* Wv1_t  = us + uo;  uo += (size_t)4096 * 768;
    ushort_t* Wout_t = us + uo;  uo += (size_t)768 * 768;
    ushort_t* outp_b = us + uo;  uo += (size_t)M * 768;

    mega<<<NBLK, 256, 0, stream>>>(
        x, context, Wq, Wk, Wv1, ln_g, ln_b, Wc, Wout,
        cnt, S, colsum, colsumsq,
        x_b, ctx_b, qb, kb, h1t, Wq_t, Wk_t, Wv1_t, Wout_t, outp_b, out,
        b, n);
}

// Round 13
// 207.078 us; speedup vs baseline: 2.4884x; 2.4884x over previous
//
#include <hip/hip_runtime.h>
#include <math.h>

typedef unsigned short ushort_t;
typedef __bf16 bf16x8 __attribute__((ext_vector_type(8)));
typedef float f32x4 __attribute__((ext_vector_type(4)));

// ---------------------------------------------------------------------------
// fp32 <-> bf16 helpers
// ---------------------------------------------------------------------------
__device__ __forceinline__ ushort_t f2b_rne(float f) {
    union { float f; unsigned int u; } c;
    c.f = f;
    unsigned int u = c.u;
    u += 0x7FFFu + ((u >> 16) & 1u);
    return (ushort_t)(u >> 16);
}
__device__ __forceinline__ float b2f(ushort_t v) {
    union { unsigned int u; float f; } c;
    c.u = ((unsigned int)v) << 16;
    return c.f;
}

// async global->LDS DMA, 16B per lane.
__device__ __forceinline__ void gl_lds16(const ushort_t* g, ushort_t* l) {
    __builtin_amdgcn_global_load_lds(
        (const __attribute__((address_space(1))) void*)g,
        (__attribute__((address_space(3))) void*)l, 16, 0, 0);
}

// ---------------------------------------------------------------------------
// prep: all bf16 conversions + zeroing of LN colsum accumulators.
// ---------------------------------------------------------------------------
__global__ __launch_bounds__(256) void prep(
    const float* __restrict__ x, const float* __restrict__ context,
    const float* __restrict__ Wq, const float* __restrict__ Wk,
    const float* __restrict__ Wv1, const float* __restrict__ Wout,
    ushort_t* __restrict__ x_b, ushort_t* __restrict__ ctx_b,
    ushort_t* __restrict__ Wq_t, ushort_t* __restrict__ Wk_t,
    ushort_t* __restrict__ Wv1_t, ushort_t* __restrict__ Wout_t,
    float* __restrict__ colzero,   // colsum|colsumsq, 2*Mn floats
    int b, int n) {
    const int t = threadIdx.x;
    const int bid = blockIdx.x;
    const int nb_x = (b * 64 * 768 / 4) / 256;
    const int nb_c = (b * n * 768 / 4) / 256;

    if (bid < nb_x + nb_c) {  // flat converts
        const float* in = (bid < nb_x) ? x : context;
        ushort_t* outp = (bid < nb_x) ? x_b : ctx_b;
        const int i = ((bid < nb_x) ? bid : (bid - nb_x)) * 256 + t;
        float4 v = ((const float4*)in)[i];
        ushort_t o[4] = {f2b_rne(v.x), f2b_rne(v.y), f2b_rne(v.z), f2b_rne(v.w)};
        *(uint2*)&outp[(size_t)i * 4] = *(uint2*)o;
        return;
    }

    int u = bid - nb_x - nb_c;
    if (u >= 4800) {  // zero colsum/colsumsq: 8 blocks x 256 x float4
        const int idx = (u - 4800) * 256 + t;
        ((float4*)colzero)[idx] = make_float4(0.f, 0.f, 0.f, 0.f);
        return;
    }

    // transposes: Wq 576, Wk 576, Wv1 3072, Wout 576
    const float* in;
    ushort_t* outp;
    int R = 768, C = 768;
    if (u < 576)        { in = Wq;  outp = Wq_t; }
    else if (u < 1152)  { u -= 576;  in = Wk;  outp = Wk_t; }
    else if (u < 4224)  { u -= 1152; in = Wv1; outp = Wv1_t; C = 4096; }
    else                { u -= 4224; in = Wout; outp = Wout_t; }
    const int ct = C / 32;
    const int c0 = (u % ct) * 32, r0 = (u / ct) * 32;
    const int tx = t & 31, ty = t >> 5;

    __shared__ float tt[32][33];
#pragma unroll
    for (int i = 0; i < 4; i++)
        tt[ty + 8 * i][tx] = in[(size_t)(r0 + ty + 8 * i) * C + c0 + tx];
    __syncthreads();
#pragma unroll
    for (int i = 0; i < 4; i++)
        outp[(size_t)(c0 + ty + 8 * i) * R + r0 + tx] = f2b_rne(tt[tx][ty + 8 * i]);
}

// ---------------------------------------------------------------------------
// gemm3: q, k GEMMs + h1^T GEMM (C[c][n_glob] = Wv1t @ ctx^T) via tile list.
// m97 global_load_lds staging. Clean epilogue (VGPR 72, ~23% occupancy).
// ---------------------------------------------------------------------------
__global__ __launch_bounds__(256) void gemm3(
    const ushort_t* __restrict__ x_b, const ushort_t* __restrict__ ctx_b,
    const ushort_t* __restrict__ Wq_t, const ushort_t* __restrict__ Wk_t,
    const ushort_t* __restrict__ Wv1_t,
    ushort_t* __restrict__ qb, ushort_t* __restrict__ kb,
    ushort_t* __restrict__ h1t, int b, int n) {
    const int bid = blockIdx.x;
    const int tq = (b * 64 / 128) * 6;
    const int tk = (b * n / 128) * 6;
    const int Mn = b * n;

    const ushort_t *A, *Bt;
    ushort_t* C;
    int N, row0, col0;
    if (bid < tq) {
        A = x_b; Bt = Wq_t; C = qb; N = 768;
        row0 = (bid / 6) * 128; col0 = (bid % 6) * 128;
    } else if (bid < tq + tk) {
        const int u = bid - tq;
        A = ctx_b; Bt = Wk_t; C = kb; N = 768;
        row0 = (u / 6) * 128; col0 = (u % 6) * 128;
    } else {
        const int u = bid - tq - tk;
        A = Wv1_t; Bt = ctx_b; C = h1t; N = Mn;
        row0 = (u % 32) * 128; col0 = (u / 32) * 128;
    }
    const int K = 768;

    __shared__ ushort_t As[128 * 32];
    __shared__ ushort_t Bs[128 * 32];

    const int t = threadIdx.x;
    const int lane = t & 63;
    const int wave = t >> 6;
    const int quad = lane >> 4;
    const int l15 = lane & 15;
    const int wm = (wave >> 1) * 64;
    const int wn = (wave & 1) * 64;

    const ushort_t* ga0 = A + (size_t)(row0 + (t >> 2)) * K + (t & 3) * 8;
    const ushort_t* ga1 = ga0 + (size_t)64 * K;
    const ushort_t* gb0 = Bt + (size_t)(col0 + (t >> 2)) * K + (t & 3) * 8;
    const ushort_t* gb1 = gb0 + (size_t)64 * K;

    ushort_t* lA0 = &As[wave * 512];
    ushort_t* lA1 = &As[2048 + wave * 512];
    ushort_t* lB0 = &Bs[wave * 512];
    ushort_t* lB1 = &Bs[2048 + wave * 512];

    f32x4 acc[4][4] = {};

    for (int k0 = 0; k0 < K; k0 += 32) {
        __syncthreads();
        gl_lds16(ga0 + k0, lA0);
        gl_lds16(ga1 + k0, lA1);
        gl_lds16(gb0 + k0, lB0);
        gl_lds16(gb1 + k0, lB1);
        __syncthreads();

        bf16x8 af[4], bfr[4];
#pragma unroll
        for (int i = 0; i < 4; i++)
            af[i] = *(const bf16x8*)&As[(wm + i * 16 + l15) * 32 + quad * 8];
#pragma unroll
        for (int j = 0; j < 4; j++)
            bfr[j] = *(const bf16x8*)&Bs[(wn + j * 16 + l15) * 32 + quad * 8];
#pragma unroll
        for (int i = 0; i < 4; i++)
#pragma unroll
            for (int j = 0; j < 4; j++)
                acc[i][j] = __builtin_amdgcn_mfma_f32_16x16x32_bf16(
                    af[i], bfr[j], acc[i][j], 0, 0, 0);
    }

#pragma unroll
    for (int i = 0; i < 4; i++)
#pragma unroll
        for (int j = 0; j < 4; j++)
#pragma unroll
            for (int r = 0; r < 4; r++) {
                const int row = row0 + wm + i * 16 + quad * 4 + r;
                const int col = col0 + wn + j * 16 + l15;
                C[(size_t)row * N + col] = f2b_rne(acc[i][j][r]);
            }
}

// ---------------------------------------------------------------------------
// scores_stats: region 0 (b*8*(n/128)): S = QK^T/sqrt(96).
// region 1 (256 blocks): LN col sums of h1t, 256x256 panels, bf16x8 loads.
// ---------------------------------------------------------------------------
__global__ __launch_bounds__(256) void scores_stats(
    const ushort_t* __restrict__ qb, const ushort_t* __restrict__ kb,
    const ushort_t* __restrict__ h1t, float* __restrict__ S,
    float* __restrict__ colsum, float* __restrict__ colsumsq,
    int b, int n, int Mn) {
    __shared__ ushort_t sb[192 * 104];
    const int t = threadIdx.x;
    const int nsc = b * 8 * (n / 128);

    if (blockIdx.x >= nsc) {  // ---- LN column-sum panel (256 rows x 256 cols) ----
        const int u = blockIdx.x - nsc;
        const int rc = u >> 4;
        const int cc = u & 15;
        const int cg = t & 31;
        const int rg = t >> 5;
        const ushort_t* p =
            h1t + (size_t)(rc * 256 + rg * 32) * Mn + cc * 256 + cg * 8;
        float s[8] = {}, s2[8] = {};
#pragma unroll 4
        for (int r = 0; r < 32; r++) {
            const bf16x8 v = *(const bf16x8*)&p[(size_t)r * Mn];
#pragma unroll
            for (int j = 0; j < 8; j++) {
                const float f = (float)v[j];
                s[j] += f;
                s2[j] += f * f;
            }
        }
        float* red = (float*)sb;
#pragma unroll
        for (int j = 0; j < 8; j++) {
            red[rg * 256 + cg * 8 + j] = s[j];
            red[2048 + rg * 256 + cg * 8 + j] = s2[j];
        }
        __syncthreads();
        float ts = 0.f, ts2 = 0.f;
#pragma unroll
        for (int g = 0; g < 8; g++) {
            ts += red[g * 256 + t];
            ts2 += red[2048 + g * 256 + t];
        }
        atomicAdd(&colsum[cc * 256 + t], ts);
        atomicAdd(&colsumsq[cc * 256 + t], ts2);
        return;
    }

    // ---- scores tile ----
    const int nt = n / 128;
    const int n0 = (blockIdx.x % nt) * 128;
    const int bh = blockIdx.x / nt;
    const int bb = bh >> 3, h = bh & 7;
    const int lane = t & 63, wave = t >> 6;
    const int quad = lane >> 4, l15 = lane & 15;
    const int wm = (wave >> 1) * 32;
    const int wn = (wave & 1) * 64;

    ushort_t* Qs = sb;
    ushort_t* Ks = sb + 64 * 104;

    for (int g = t; g < 768; g += 256) {
        const int r = g / 12, s = g - r * 12;
        *(bf16x8*)&Qs[r * 104 + s * 8] =
            *(const bf16x8*)&qb[(size_t)(bb * 64 + r) * 768 + h * 96 + s * 8];
    }
    for (int g = t; g < 1536; g += 256) {
        const int r = g / 12, s = g - r * 12;
        *(bf16x8*)&Ks[r * 104 + s * 8] =
            *(const bf16x8*)&kb[(size_t)(bb * n + n0 + r) * 768 + h * 96 + s * 8];
    }
    __syncthreads();

    f32x4 acc[2][4] = {};
#pragma unroll
    for (int ks = 0; ks < 3; ks++) {
        bf16x8 af[2], bfr[4];
#pragma unroll
        for (int i = 0; i < 2; i++)
            af[i] = *(const bf16x8*)&Qs[(wm + i * 16 + l15) * 104 + ks * 32 + quad * 8];
#pragma unroll
        for (int j = 0; j < 4; j++)
            bfr[j] = *(const bf16x8*)&Ks[(wn + j * 16 + l15) * 104 + ks * 32 + quad * 8];
#pragma unroll
        for (int i = 0; i < 2; i++)
#pragma unroll
            for (int j = 0; j < 4; j++)
                acc[i][j] = __builtin_amdgcn_mfma_f32_16x16x32_bf16(
                    af[i], bfr[j], acc[i][j], 0, 0, 0);
    }

    const float sc = 0.10206207261596575f;  // 1/sqrt(96)
    float* Sp = S + (size_t)bh * 64 * n;
#pragma unroll
    for (int i = 0; i < 2; i++)
#pragma unroll
        for (int j = 0; j < 4; j++)
#pragma unroll
            for (int r = 0; r < 4; r++) {
                const int row = wm + i * 16 + quad * 4 + r;
                const int col = n0 + wn + j * 16 + l15;
                Sp[(size_t)row * n + col] = acc[i][j][r] * sc;
            }
}

// ---------------------------------------------------------------------------
// attn_fused (512 thr / 8 waves): one block per (b,qi). Per-wave softmax for
// its head; w bf16 in LDS (A-operand rows 0..7, row 8 zeros); PV via
// mfma_16x16x32 over 256-chunks of h1t; LN affine + Wc apply -> row in LDS;
// then FUSED Wout matvec: out[bq,:] = row @ Wout (bf16 weights, fp32 acc).
// ---------------------------------------------------------------------------
__global__ __launch_bounds__(512) void attn_fused(
    const float* __restrict__ S, const float* __restrict__ colsum,
    const float* __restrict__ colsumsq, const ushort_t* __restrict__ h1t,
    const float* __restrict__ ln_g, const float* __restrict__ ln_b,
    const float* __restrict__ Wc, const ushort_t* __restrict__ Wout_t,
    float* __restrict__ out, int n, int Mn) {
    const int bq = blockIdx.x;
    const int bb = bq >> 6, qi = bq & 63;
    const int tid = threadIdx.x;
    const int lane = tid & 63, wv = tid >> 6;   // wv 0..7
    const int quad = lane >> 4, l15 = lane & 15;

    __shared__ ushort_t sW[9 * 1032];   // rows 0..7 = w[h], row 8 = zeros
    __shared__ ushort_t sH[64 * 264];   // H chunk; first 8KB doubles as mu/rstd
    __shared__ float sm[8], sl[8], swmu[8];
    __shared__ float sA[512];
    __shared__ float sO[768];           // out_pre row (bf16-rounded)

    float* sMu = (float*)sH;            // [1024] (overwritten by chunk 0 stage)
    float* sRs = (float*)sH + 1024;     // [1024]

    // LN stats from column sums
    for (int i = tid; i < n; i += 512) {
        const float cs = colsum[bb * n + i];
        const float cq = colsumsq[bb * n + i];
        const float m = cs * (1.0f / 4096.0f);
        sMu[i] = m;
        sRs[i] = rsqrtf(cq * (1.0f / 4096.0f) - m * m + 1e-5f);
    }
    // zero row 8 of sW
    for (int i = tid; i < 1032; i += 512) sW[8 * 1032 + i] = 0;
    __syncthreads();

    // per-wave softmax stats + w for h = wv
    {
        const int h = wv;
        const float* Sp = S + ((size_t)(bb * 8 + h) * 64 + qi) * n;
        float m = -1e30f;
        for (int i = lane; i < n; i += 64) m = fmaxf(m, Sp[i]);
#pragma unroll
        for (int off = 32; off > 0; off >>= 1) m = fmaxf(m, __shfl_down(m, off));
        m = __shfl(m, 0);
        float l = 0.f, wm = 0.f;
        for (int i = lane; i < n; i += 64) {
            const float e = expf(Sp[i] - m);
            const float w = e * sRs[i];
            const ushort_t wb = f2b_rne(w);
            sW[h * 1032 + i] = wb;
            l += e;
            wm += b2f(wb) * sMu[i];
        }
#pragma unroll
        for (int off = 32; off > 0; off >>= 1) {
            l += __shfl_down(l, off);
            wm += __shfl_down(wm, off);
        }
        if (lane == 0) { sm[h] = m; sl[h] = l; swmu[h] = wm; }
    }

    // PV via MFMA: C[h(16)][r(64)] = w @ H^T, K = n in 256-chunks.
    const int mrow = (l15 < 8 ? l15 : 8) * 1032;
    f32x4 acc[4] = {};
    const int nch = n >> 8;
    for (int ch = 0; ch < nch; ch++) {
        __syncthreads();
        for (int g = tid; g < 2048; g += 512) {
            const int row = g >> 5, seg = g & 31;
            *(bf16x8*)&sH[row * 264 + seg * 8] =
                *(const bf16x8*)&h1t[(size_t)(qi * 64 + row) * Mn + bb * n +
                                     ch * 256 + seg * 8];
        }
        __syncthreads();
#pragma unroll
        for (int ks = 0; ks < 8; ks++) {
            const bf16x8 af = *(const bf16x8*)&sW[mrow + ch * 256 + ks * 32 + quad * 8];
#pragma unroll
            for (int j = 0; j < 4; j++) {
                const bf16x8 bf = *(const bf16x8*)&sH[(j * 16 + l15) * 264 + ks * 32 + quad * 8];
                acc[j] = __builtin_amdgcn_mfma_f32_16x16x32_bf16(af, bf, acc[j], 0, 0, 0);
            }
        }
    }
    __syncthreads();

    // epilogue: rows h = quad*4+r (<8), col = j*16+l15. wave 0 writes.
    if (wv == 0) {
#pragma unroll
        for (int j = 0; j < 4; j++)
#pragma unroll
            for (int r = 0; r < 4; r++) {
                const int h = quad * 4 + r;
                if (h < 8) {
                    const int rr = j * 16 + l15;
                    const int c = qi * 64 + rr;
                    sA[h * 64 + rr] =
                        ln_g[c] * ((acc[j][r] - swmu[h]) / sl[h]) + ln_b[c];
                }
            }
    }
    __syncthreads();

    // Wc apply -> out_pre row in LDS (bf16-rounded for parity with prior path)
    for (int d = tid; d < 768; d += 512) {
        const int h = d / 96;
        const float* wp = Wc + (size_t)qi * 49152 + d;
        float a = 0.f;
#pragma unroll
        for (int r = 0; r < 64; r++) a += sA[h * 64 + r] * wp[(size_t)r * 768];
        sO[d] = b2f(f2b_rne(a));
    }
    __syncthreads();

    // Fused Wout matvec: out[bq][dout] = sum_d sO[d] * Wout_t[dout][d]
    for (int dout = tid; dout < 768; dout += 512) {
        const ushort_t* wrow = Wout_t + (size_t)dout * 768;
        float a = 0.f;
#pragma unroll 4
        for (int d8 = 0; d8 < 96; d8++) {
            const bf16x8 wv8 = *(const bf16x8*)&wrow[d8 * 8];
            const float* so = &sO[d8 * 8];
#pragma unroll
            for (int j = 0; j < 8; j++) a += so[j] * (float)wv8[j];
        }
        out[(size_t)bq * 768 + dout] = a;
    }
}

// ---------------------------------------------------------------------------
extern "C" void kernel_launch(void* const* d_in, const int* in_sizes, int n_in,
                              void* d_out, int out_size, void* d_ws, size_t ws_size,
                              hipStream_t stream) {
    const float* x       = (const float*)d_in[0];
    const float* context = (const float*)d_in[1];
    const float* Wq      = (const float*)d_in[2];
    const float* Wk      = (const float*)d_in[3];
    const float* Wv1     = (const float*)d_in[4];
    const float* ln_g    = (const float*)d_in[5];
    const float* ln_b    = (const float*)d_in[6];
    const float* Wc      = (const float*)d_in[7];
    const float* Wout    = (const float*)d_in[8];
    float* out = (float*)d_out;

    const int b = in_sizes[0] / (64 * 768);
    const int n = in_sizes[1] / (b * 768);
    const int M  = b * 64;     // 256
    const int Mn = b * n;      // 4096

    float* ws = (float*)d_ws;
    size_t off = 0;
    float* S       = ws + off;  off += (size_t)b * 8 * 64 * n;
    float* colsum  = ws + off;  off += (size_t)Mn;
    float* colsumsq= ws + off;  off += (size_t)Mn;

    ushort_t* us = (ushort_t*)(ws + off);
    size_t uo = 0;
    ushort_t* x_b    = us + uo;  uo += (size_t)M * 768;
    ushort_t* ctx_b  = us + uo;  uo += (size_t)Mn * 768;
    ushort_t* qb     = us + uo;  uo += (size_t)M * 768;
    ushort_t* kb     = us + uo;  uo += (size_t)Mn * 768;
    ushort_t* h1t    = us + uo;  uo += (size_t)Mn * 4096;   // [c][n_glob]
    ushort_t* Wq_t   = us + uo;  uo += (size_t)768 * 768;
    ushort_t* Wk_t   = us + uo;  uo += (size_t)768 * 768;
    ushort_t* Wv1_t  = us + uo;  uo += (size_t)4096 * 768;
    ushort_t* Wout_t = us + uo;  uo += (size_t)768 * 768;

    // 1. conversions + zero LN accumulators
    const int nb_x = (M * 768 / 4) / 256;
    const int nb_c = (Mn * 768 / 4) / 256;
    prep<<<nb_x + nb_c + 4800 + 8, 256, 0, stream>>>(
        x, context, Wq, Wk, Wv1, Wout, x_b, ctx_b, Wq_t, Wk_t, Wv1_t, Wout_t,
        colsum, b, n);

    // 2. q, k, h1^T GEMMs
    const int tq = (M / 128) * 6, tk = (Mn / 128) * 6;
    const int th = (4096 / 128) * (Mn / 128);
    gemm3<<<tq + tk + th, 256, 0, stream>>>(x_b, ctx_b, Wq_t, Wk_t, Wv1_t,
                                            qb, kb, h1t, b, n);

    // 3. scores + LN column sums
    scores_stats<<<b * 8 * (n / 128) + 256, 256, 0, stream>>>(
        qb, kb, h1t, S, colsum, colsumsq, b, n, Mn);

    // 4. fused softmax + PV-MFMA + LN affine + Wc + Wout matvec
    attn_fused<<<M, 512, 0, stream>>>(S, colsum, colsumsq, h1t, ln_g, ln_b,
                                      Wc, Wout_t, out, n, Mn);
}

// Round 14
// 186.551 us; speedup vs baseline: 2.7622x; 1.1100x over previous
//
#include <hip/hip_runtime.h>
#include <math.h>

typedef unsigned short ushort_t;
typedef __bf16 bf16x8 __attribute__((ext_vector_type(8)));
typedef float f32x4 __attribute__((ext_vector_type(4)));

// ---------------------------------------------------------------------------
// fp32 <-> bf16 helpers
// ---------------------------------------------------------------------------
__device__ __forceinline__ ushort_t f2b_rne(float f) {
    union { float f; unsigned int u; } c;
    c.f = f;
    unsigned int u = c.u;
    u += 0x7FFFu + ((u >> 16) & 1u);
    return (ushort_t)(u >> 16);
}
__device__ __forceinline__ float b2f(ushort_t v) {
    union { unsigned int u; float f; } c;
    c.u = ((unsigned int)v) << 16;
    return c.f;
}

// async global->LDS DMA, 16B per lane.
__device__ __forceinline__ void gl_lds16(const ushort_t* g, ushort_t* l) {
    __builtin_amdgcn_global_load_lds(
        (const __attribute__((address_space(1))) void*)g,
        (__attribute__((address_space(3))) void*)l, 16, 0, 0);
}

// ---------------------------------------------------------------------------
// prep: all bf16 conversions + zeroing of LN colsum accumulators.
// ---------------------------------------------------------------------------
__global__ __launch_bounds__(256) void prep(
    const float* __restrict__ x, const float* __restrict__ context,
    const float* __restrict__ Wq, const float* __restrict__ Wk,
    const float* __restrict__ Wv1, const float* __restrict__ Wout,
    ushort_t* __restrict__ x_b, ushort_t* __restrict__ ctx_b,
    ushort_t* __restrict__ Wq_t, ushort_t* __restrict__ Wk_t,
    ushort_t* __restrict__ Wv1_t, ushort_t* __restrict__ Wout_t,
    float* __restrict__ colzero,   // colsum|colsumsq, 2*Mn floats
    int b, int n) {
    const int t = threadIdx.x;
    const int bid = blockIdx.x;
    const int nb_x = (b * 64 * 768 / 4) / 256;
    const int nb_c = (b * n * 768 / 4) / 256;

    if (bid < nb_x + nb_c) {  // flat converts
        const float* in = (bid < nb_x) ? x : context;
        ushort_t* outp = (bid < nb_x) ? x_b : ctx_b;
        const int i = ((bid < nb_x) ? bid : (bid - nb_x)) * 256 + t;
        float4 v = ((const float4*)in)[i];
        ushort_t o[4] = {f2b_rne(v.x), f2b_rne(v.y), f2b_rne(v.z), f2b_rne(v.w)};
        *(uint2*)&outp[(size_t)i * 4] = *(uint2*)o;
        return;
    }

    int u = bid - nb_x - nb_c;
    if (u >= 4800) {  // zero colsum/colsumsq: 8 blocks x 256 x float4
        const int idx = (u - 4800) * 256 + t;
        ((float4*)colzero)[idx] = make_float4(0.f, 0.f, 0.f, 0.f);
        return;
    }

    // transposes: Wq 576, Wk 576, Wv1 3072, Wout 576
    const float* in;
    ushort_t* outp;
    int R = 768, C = 768;
    if (u < 576)        { in = Wq;  outp = Wq_t; }
    else if (u < 1152)  { u -= 576;  in = Wk;  outp = Wk_t; }
    else if (u < 4224)  { u -= 1152; in = Wv1; outp = Wv1_t; C = 4096; }
    else                { u -= 4224; in = Wout; outp = Wout_t; }
    const int ct = C / 32;
    const int c0 = (u % ct) * 32, r0 = (u / ct) * 32;
    const int tx = t & 31, ty = t >> 5;

    __shared__ float tt[32][33];
#pragma unroll
    for (int i = 0; i < 4; i++)
        tt[ty + 8 * i][tx] = in[(size_t)(r0 + ty + 8 * i) * C + c0 + tx];
    __syncthreads();
#pragma unroll
    for (int i = 0; i < 4; i++)
        outp[(size_t)(c0 + ty + 8 * i) * R + r0 + tx] = f2b_rne(tt[tx][ty + 8 * i]);
}

// ---------------------------------------------------------------------------
// gemm3: q, k GEMMs + h1^T GEMM (C[c][n_glob] = Wv1t @ ctx^T) via tile list.
// m97 global_load_lds staging. Clean epilogue (VGPR 72, ~23% occupancy).
// ---------------------------------------------------------------------------
__global__ __launch_bounds__(256) void gemm3(
    const ushort_t* __restrict__ x_b, const ushort_t* __restrict__ ctx_b,
    const ushort_t* __restrict__ Wq_t, const ushort_t* __restrict__ Wk_t,
    const ushort_t* __restrict__ Wv1_t,
    ushort_t* __restrict__ qb, ushort_t* __restrict__ kb,
    ushort_t* __restrict__ h1t, int b, int n) {
    const int bid = blockIdx.x;
    const int tq = (b * 64 / 128) * 6;
    const int tk = (b * n / 128) * 6;
    const int Mn = b * n;

    const ushort_t *A, *Bt;
    ushort_t* C;
    int N, row0, col0;
    if (bid < tq) {
        A = x_b; Bt = Wq_t; C = qb; N = 768;
        row0 = (bid / 6) * 128; col0 = (bid % 6) * 128;
    } else if (bid < tq + tk) {
        const int u = bid - tq;
        A = ctx_b; Bt = Wk_t; C = kb; N = 768;
        row0 = (u / 6) * 128; col0 = (u % 6) * 128;
    } else {
        const int u = bid - tq - tk;
        A = Wv1_t; Bt = ctx_b; C = h1t; N = Mn;
        row0 = (u % 32) * 128; col0 = (u / 32) * 128;
    }
    const int K = 768;

    __shared__ ushort_t As[128 * 32];
    __shared__ ushort_t Bs[128 * 32];

    const int t = threadIdx.x;
    const int lane = t & 63;
    const int wave = t >> 6;
    const int quad = lane >> 4;
    const int l15 = lane & 15;
    const int wm = (wave >> 1) * 64;
    const int wn = (wave & 1) * 64;

    const ushort_t* ga0 = A + (size_t)(row0 + (t >> 2)) * K + (t & 3) * 8;
    const ushort_t* ga1 = ga0 + (size_t)64 * K;
    const ushort_t* gb0 = Bt + (size_t)(col0 + (t >> 2)) * K + (t & 3) * 8;
    const ushort_t* gb1 = gb0 + (size_t)64 * K;

    ushort_t* lA0 = &As[wave * 512];
    ushort_t* lA1 = &As[2048 + wave * 512];
    ushort_t* lB0 = &Bs[wave * 512];
    ushort_t* lB1 = &Bs[2048 + wave * 512];

    f32x4 acc[4][4] = {};

    for (int k0 = 0; k0 < K; k0 += 32) {
        __syncthreads();
        gl_lds16(ga0 + k0, lA0);
        gl_lds16(ga1 + k0, lA1);
        gl_lds16(gb0 + k0, lB0);
        gl_lds16(gb1 + k0, lB1);
        __syncthreads();

        bf16x8 af[4], bfr[4];
#pragma unroll
        for (int i = 0; i < 4; i++)
            af[i] = *(const bf16x8*)&As[(wm + i * 16 + l15) * 32 + quad * 8];
#pragma unroll
        for (int j = 0; j < 4; j++)
            bfr[j] = *(const bf16x8*)&Bs[(wn + j * 16 + l15) * 32 + quad * 8];
#pragma unroll
        for (int i = 0; i < 4; i++)
#pragma unroll
            for (int j = 0; j < 4; j++)
                acc[i][j] = __builtin_amdgcn_mfma_f32_16x16x32_bf16(
                    af[i], bfr[j], acc[i][j], 0, 0, 0);
    }

#pragma unroll
    for (int i = 0; i < 4; i++)
#pragma unroll
        for (int j = 0; j < 4; j++)
#pragma unroll
            for (int r = 0; r < 4; r++) {
                const int row = row0 + wm + i * 16 + quad * 4 + r;
                const int col = col0 + wn + j * 16 + l15;
                C[(size_t)row * N + col] = f2b_rne(acc[i][j][r]);
            }
}

// ---------------------------------------------------------------------------
// scores_stats: region 0 (b*8*(n/128)): S = QK^T/sqrt(96).
// region 1 (256 blocks): LN col sums of h1t, 256x256 panels, bf16x8 loads.
// ---------------------------------------------------------------------------
__global__ __launch_bounds__(256) void scores_stats(
    const ushort_t* __restrict__ qb, const ushort_t* __restrict__ kb,
    const ushort_t* __restrict__ h1t, float* __restrict__ S,
    float* __restrict__ colsum, float* __restrict__ colsumsq,
    int b, int n, int Mn) {
    __shared__ ushort_t sb[192 * 104];
    const int t = threadIdx.x;
    const int nsc = b * 8 * (n / 128);

    if (blockIdx.x >= nsc) {  // ---- LN column-sum panel (256 rows x 256 cols) ----
        const int u = blockIdx.x - nsc;
        const int rc = u >> 4;
        const int cc = u & 15;
        const int cg = t & 31;
        const int rg = t >> 5;
        const ushort_t* p =
            h1t + (size_t)(rc * 256 + rg * 32) * Mn + cc * 256 + cg * 8;
        float s[8] = {}, s2[8] = {};
#pragma unroll 4
        for (int r = 0; r < 32; r++) {
            const bf16x8 v = *(const bf16x8*)&p[(size_t)r * Mn];
#pragma unroll
            for (int j = 0; j < 8; j++) {
                const float f = (float)v[j];
                s[j] += f;
                s2[j] += f * f;
            }
        }
        float* red = (float*)sb;
#pragma unroll
        for (int j = 0; j < 8; j++) {
            red[rg * 256 + cg * 8 + j] = s[j];
            red[2048 + rg * 256 + cg * 8 + j] = s2[j];
        }
        __syncthreads();
        float ts = 0.f, ts2 = 0.f;
#pragma unroll
        for (int g = 0; g < 8; g++) {
            ts += red[g * 256 + t];
            ts2 += red[2048 + g * 256 + t];
        }
        atomicAdd(&colsum[cc * 256 + t], ts);
        atomicAdd(&colsumsq[cc * 256 + t], ts2);
        return;
    }

    // ---- scores tile ----
    const int nt = n / 128;
    const int n0 = (blockIdx.x % nt) * 128;
    const int bh = blockIdx.x / nt;
    const int bb = bh >> 3, h = bh & 7;
    const int lane = t & 63, wave = t >> 6;
    const int quad = lane >> 4, l15 = lane & 15;
    const int wm = (wave >> 1) * 32;
    const int wn = (wave & 1) * 64;

    ushort_t* Qs = sb;
    ushort_t* Ks = sb + 64 * 104;

    for (int g = t; g < 768; g += 256) {
        const int r = g / 12, s = g - r * 12;
        *(bf16x8*)&Qs[r * 104 + s * 8] =
            *(const bf16x8*)&qb[(size_t)(bb * 64 + r) * 768 + h * 96 + s * 8];
    }
    for (int g = t; g < 1536; g += 256) {
        const int r = g / 12, s = g - r * 12;
        *(bf16x8*)&Ks[r * 104 + s * 8] =
            *(const bf16x8*)&kb[(size_t)(bb * n + n0 + r) * 768 + h * 96 + s * 8];
    }
    __syncthreads();

    f32x4 acc[2][4] = {};
#pragma unroll
    for (int ks = 0; ks < 3; ks++) {
        bf16x8 af[2], bfr[4];
#pragma unroll
        for (int i = 0; i < 2; i++)
            af[i] = *(const bf16x8*)&Qs[(wm + i * 16 + l15) * 104 + ks * 32 + quad * 8];
#pragma unroll
        for (int j = 0; j < 4; j++)
            bfr[j] = *(const bf16x8*)&Ks[(wn + j * 16 + l15) * 104 + ks * 32 + quad * 8];
#pragma unroll
        for (int i = 0; i < 2; i++)
#pragma unroll
            for (int j = 0; j < 4; j++)
                acc[i][j] = __builtin_amdgcn_mfma_f32_16x16x32_bf16(
                    af[i], bfr[j], acc[i][j], 0, 0, 0);
    }

    const float sc = 0.10206207261596575f;  // 1/sqrt(96)
    float* Sp = S + (size_t)bh * 64 * n;
#pragma unroll
    for (int i = 0; i < 2; i++)
#pragma unroll
        for (int j = 0; j < 4; j++)
#pragma unroll
            for (int r = 0; r < 4; r++) {
                const int row = wm + i * 16 + quad * 4 + r;
                const int col = n0 + wn + j * 16 + l15;
                Sp[(size_t)row * n + col] = acc[i][j][r] * sc;
            }
}

// ---------------------------------------------------------------------------
// attn_fused (1024 thr / 16 waves): one block per (b,qi).
// - softmax: 2 waves per head, each covering half of n; partial max/l/wmu
//   merged through LDS (exact split-merge algebra).
// - PV MFMA: only waves 0..3, each owning one 16-col j-block (no redundancy).
// - Wc apply -> outp_b (bf16); final GEMM stays a separate dispatch.
// ---------------------------------------------------------------------------
__global__ __launch_bounds__(1024) void attn_fused(
    const float* __restrict__ S, const float* __restrict__ colsum,
    const float* __restrict__ colsumsq, const ushort_t* __restrict__ h1t,
    const float* __restrict__ ln_g, const float* __restrict__ ln_b,
    const float* __restrict__ Wc, ushort_t* __restrict__ outp,
    int n, int Mn) {
    const int bq = blockIdx.x;
    const int bb = bq >> 6, qi = bq & 63;
    const int tid = threadIdx.x;
    const int lane = tid & 63, wv = tid >> 6;   // wv 0..15
    const int quad = lane >> 4, l15 = lane & 15;

    __shared__ ushort_t sW[9 * 1032];   // rows 0..7 = w[h], row 8 = zeros
    __shared__ ushort_t sH[64 * 264];   // H chunk; overlay: mu/rstd before PV
    __shared__ float sl[8], swmu[8];
    __shared__ float pm[16], pl[16], pwm[16];
    __shared__ float sA[512];

    float* sMu = (float*)sH;            // [1024] (overwritten by chunk 0 stage)
    float* sRs = (float*)sH + 1024;     // [1024]

    // LN stats from column sums
    for (int i = tid; i < n; i += 1024) {
        const float cs = colsum[bb * n + i];
        const float cq = colsumsq[bb * n + i];
        const float m = cs * (1.0f / 4096.0f);
        sMu[i] = m;
        sRs[i] = rsqrtf(cq * (1.0f / 4096.0f) - m * m + 1e-5f);
    }
    // zero row 8 of sW
    for (int i = tid; i < 1032; i += 1024) sW[8 * 1032 + i] = 0;
    __syncthreads();

    // softmax: head h = wv>>1; each wave handles half of n.
    const int h = wv >> 1;
    const int half = wv & 1;
    const int nh = n >> 1;
    const int i0 = half * nh;
    const float* Sp = S + ((size_t)(bb * 8 + h) * 64 + qi) * n;
    {
        float m = -1e30f;
        for (int i = i0 + lane; i < i0 + nh; i += 64) m = fmaxf(m, Sp[i]);
#pragma unroll
        for (int off = 32; off > 0; off >>= 1) m = fmaxf(m, __shfl_down(m, off));
        if (lane == 0) pm[wv] = m;
    }
    __syncthreads();
    const float mh = fmaxf(pm[2 * h], pm[2 * h + 1]);
    {
        float l = 0.f, wm = 0.f;
        for (int i = i0 + lane; i < i0 + nh; i += 64) {
            const float e = expf(Sp[i] - mh);
            const float w = e * sRs[i];
            const ushort_t wb = f2b_rne(w);
            sW[h * 1032 + i] = wb;
            l += e;
            wm += b2f(wb) * sMu[i];
        }
#pragma unroll
        for (int off = 32; off > 0; off >>= 1) {
            l += __shfl_down(l, off);
            wm += __shfl_down(wm, off);
        }
        if (lane == 0) { pl[wv] = l; pwm[wv] = wm; }
    }
    __syncthreads();
    if (tid < 8) {
        sl[tid] = pl[2 * tid] + pl[2 * tid + 1];
        swmu[tid] = pwm[2 * tid] + pwm[2 * tid + 1];
    }

    // PV via MFMA: C[h(16)][r(64)] = w @ H^T, K = n in 256-chunks.
    // Waves 0..3 each own j = wv (cols j*16..j*16+15).
    const int mrow = (l15 < 8 ? l15 : 8) * 1032;
    f32x4 acc = {};
    const int nch = n >> 8;
    for (int ch = 0; ch < nch; ch++) {
        __syncthreads();  // chunk0: also protects sMu/sRs overlay + sW writes
        for (int g = tid; g < 2048; g += 1024) {
            const int row = g >> 5, seg = g & 31;
            *(bf16x8*)&sH[row * 264 + seg * 8] =
                *(const bf16x8*)&h1t[(size_t)(qi * 64 + row) * Mn + bb * n +
                                     ch * 256 + seg * 8];
        }
        __syncthreads();
        if (wv < 4) {
#pragma unroll
            for (int ks = 0; ks < 8; ks++) {
                const bf16x8 af = *(const bf16x8*)&sW[mrow + ch * 256 + ks * 32 + quad * 8];
                const bf16x8 bf = *(const bf16x8*)&sH[(wv * 16 + l15) * 264 + ks * 32 + quad * 8];
                acc = __builtin_amdgcn_mfma_f32_16x16x32_bf16(af, bf, acc, 0, 0, 0);
            }
        }
    }
    __syncthreads();

    // epilogue: wave j=wv<4 holds cols wv*16+l15, rows quad*4+r.
    if (wv < 4) {
#pragma unroll
        for (int r = 0; r < 4; r++) {
            const int hh = quad * 4 + r;
            if (hh < 8) {
                const int rr = wv * 16 + l15;
                const int c = qi * 64 + rr;
                sA[hh * 64 + rr] =
                    ln_g[c] * ((acc[r] - swmu[hh]) / sl[hh]) + ln_b[c];
            }
        }
    }
    __syncthreads();

    // Wc apply -> outp (bf16)
    for (int d = tid; d < 768; d += 1024) {
        const int hh = d / 96;
        const float* wp = Wc + (size_t)qi * 49152 + d;
        float a = 0.f;
#pragma unroll
        for (int r = 0; r < 64; r++) a += sA[hh * 64 + r] * wp[(size_t)r * 768];
        outp[(size_t)bq * 768 + d] = f2b_rne(a);
    }
}

// ---------------------------------------------------------------------------
// Final out = outp_b @ Wout_t^T, fp32 out.
// ---------------------------------------------------------------------------
__global__ __launch_bounds__(256) void gemm_out(const ushort_t* __restrict__ A,
                                                const ushort_t* __restrict__ Bt,
                                                float* __restrict__ C,
                                                int M, int N, int K) {
    __shared__ ushort_t As[128 * 40];
    __shared__ ushort_t Bs[128 * 40];

    const int t = threadIdx.x;
    const int lane = t & 63;
    const int wave = t >> 6;
    const int quad = lane >> 4;
    const int l15 = lane & 15;
    const int wm = (wave >> 1) * 64;
    const int wn = (wave & 1) * 64;
    const int row0 = blockIdx.y * 128, col0 = blockIdx.x * 128;

    const int srow = t >> 2;
    const int sseg = t & 3;
    const ushort_t* ga0 = A + (size_t)(row0 + srow) * K + sseg * 8;
    const ushort_t* ga1 = A + (size_t)(row0 + srow + 64) * K + sseg * 8;
    const ushort_t* gb0 = Bt + (size_t)(col0 + srow) * K + sseg * 8;
    const ushort_t* gb1 = Bt + (size_t)(col0 + srow + 64) * K + sseg * 8;

    f32x4 acc[4][4] = {};

    bf16x8 ra0 = *(const bf16x8*)ga0;
    bf16x8 ra1 = *(const bf16x8*)ga1;
    bf16x8 rb0 = *(const bf16x8*)gb0;
    bf16x8 rb1 = *(const bf16x8*)gb1;

    for (int k0 = 0; k0 < K; k0 += 32) {
        __syncthreads();
        *(bf16x8*)&As[srow * 40 + sseg * 8] = ra0;
        *(bf16x8*)&As[(srow + 64) * 40 + sseg * 8] = ra1;
        *(bf16x8*)&Bs[srow * 40 + sseg * 8] = rb0;
        *(bf16x8*)&Bs[(srow + 64) * 40 + sseg * 8] = rb1;
        __syncthreads();
        if (k0 + 32 < K) {
            ra0 = *(const bf16x8*)(ga0 + k0 + 32);
            ra1 = *(const bf16x8*)(ga1 + k0 + 32);
            rb0 = *(const bf16x8*)(gb0 + k0 + 32);
            rb1 = *(const bf16x8*)(gb1 + k0 + 32);
        }
        bf16x8 af[4], bfr[4];
#pragma unroll
        for (int i = 0; i < 4; i++)
            af[i] = *(const bf16x8*)&As[(wm + i * 16 + l15) * 40 + quad * 8];
#pragma unroll
        for (int j = 0; j < 4; j++)
            bfr[j] = *(const bf16x8*)&Bs[(wn + j * 16 + l15) * 40 + quad * 8];
#pragma unroll
        for (int i = 0; i < 4; i++)
#pragma unroll
            for (int j = 0; j < 4; j++)
                acc[i][j] = __builtin_amdgcn_mfma_f32_16x16x32_bf16(
                    af[i], bfr[j], acc[i][j], 0, 0, 0);
    }

#pragma unroll
    for (int i = 0; i < 4; i++)
#pragma unroll
        for (int j = 0; j < 4; j++)
#pragma unroll
            for (int r = 0; r < 4; r++) {
                const int row = row0 + wm + i * 16 + quad * 4 + r;
                const int col = col0 + wn + j * 16 + l15;
                C[(size_t)row * N + col] = acc[i][j][r];
            }
}

// ---------------------------------------------------------------------------
extern "C" void kernel_launch(void* const* d_in, const int* in_sizes, int n_in,
                              void* d_out, int out_size, void* d_ws, size_t ws_size,
                              hipStream_t stream) {
    const float* x       = (const float*)d_in[0];
    const float* context = (const float*)d_in[1];
    const float* Wq      = (const float*)d_in[2];
    const float* Wk      = (const float*)d_in[3];
    const float* Wv1     = (const float*)d_in[4];
    const float* ln_g    = (const float*)d_in[5];
    const float* ln_b    = (const float*)d_in[6];
    const float* Wc      = (const float*)d_in[7];
    const float* Wout    = (const float*)d_in[8];
    float* out = (float*)d_out;

    const int b = in_sizes[0] / (64 * 768);
    const int n = in_sizes[1] / (b * 768);
    const int M  = b * 64;     // 256
    const int Mn = b * n;      // 4096

    float* ws = (float*)d_ws;
    size_t off = 0;
    float* S       = ws + off;  off += (size_t)b * 8 * 64 * n;
    float* colsum  = ws + off;  off += (size_t)Mn;
    float* colsumsq= ws + off;  off += (size_t)Mn;

    ushort_t* us = (ushort_t*)(ws + off);
    size_t uo = 0;
    ushort_t* x_b    = us + uo;  uo += (size_t)M * 768;
    ushort_t* ctx_b  = us + uo;  uo += (size_t)Mn * 768;
    ushort_t* qb     = us + uo;  uo += (size_t)M * 768;
    ushort_t* kb     = us + uo;  uo += (size_t)Mn * 768;
    ushort_t* h1t    = us + uo;  uo += (size_t)Mn * 4096;   // [c][n_glob]
    ushort_t* Wq_t   = us + uo;  uo += (size_t)768 * 768;
    ushort_t* Wk_t   = us + uo;  uo += (size_t)768 * 768;
    ushort_t* Wv1_t  = us + uo;  uo += (size_t)4096 * 768;
    ushort_t* Wout_t = us + uo;  uo += (size_t)768 * 768;
    ushort_t* outp_b = us + uo;  uo += (size_t)M * 768;

    // 1. conversions + zero LN accumulators
    const int nb_x = (M * 768 / 4) / 256;
    const int nb_c = (Mn * 768 / 4) / 256;
    prep<<<nb_x + nb_c + 4800 + 8, 256, 0, stream>>>(
        x, context, Wq, Wk, Wv1, Wout, x_b, ctx_b, Wq_t, Wk_t, Wv1_t, Wout_t,
        colsum, b, n);

    // 2. q, k, h1^T GEMMs
    const int tq = (M / 128) * 6, tk = (Mn / 128) * 6;
    const int th = (4096 / 128) * (Mn / 128);
    gemm3<<<tq + tk + th, 256, 0, stream>>>(x_b, ctx_b, Wq_t, Wk_t, Wv1_t,
                                            qb, kb, h1t, b, n);

    // 3. scores + LN column sums
    scores_stats<<<b * 8 * (n / 128) + 256, 256, 0, stream>>>(
        qb, kb, h1t, S, colsum, colsumsq, b, n, Mn);

    // 4. fused softmax + PV-MFMA + LN affine + Wc  (1024 thr / 16 waves)
    attn_fused<<<M, 1024, 0, stream>>>(S, colsum, colsumsq, h1t, ln_g, ln_b,
                                       Wc, outp_b, n, Mn);

    // 5. out = outp @ Wout
    gemm_out<<<dim3(6, M / 128), 256, 0, stream>>>(outp_b, Wout_t, out, M, 768, 768);
}

// Round 15
// 186.323 us; speedup vs baseline: 2.7656x; 1.0012x over previous
//
#include <hip/hip_runtime.h>
#include <math.h>

typedef unsigned short ushort_t;
typedef __bf16 bf16x8 __attribute__((ext_vector_type(8)));
typedef float f32x4 __attribute__((ext_vector_type(4)));

// ---------------------------------------------------------------------------
// fp32 <-> bf16 helpers
// ---------------------------------------------------------------------------
__device__ __forceinline__ ushort_t f2b_rne(float f) {
    union { float f; unsigned int u; } c;
    c.f = f;
    unsigned int u = c.u;
    u += 0x7FFFu + ((u >> 16) & 1u);
    return (ushort_t)(u >> 16);
}
__device__ __forceinline__ float b2f(ushort_t v) {
    union { unsigned int u; float f; } c;
    c.u = ((unsigned int)v) << 16;
    return c.f;
}

// async global->LDS DMA, 16B per lane.
__device__ __forceinline__ void gl_lds16(const ushort_t* g, ushort_t* l) {
    __builtin_amdgcn_global_load_lds(
        (const __attribute__((address_space(1))) void*)g,
        (__attribute__((address_space(3))) void*)l, 16, 0, 0);
}

// ---------------------------------------------------------------------------
// prep: all bf16 conversions + zeroing of LN colsum accumulators.
// Wout is flat-converted (NOT transposed) -> Wout_b[d][dout], so the fused
// matvec in attn_fused reads it coalesced across dout.
// ---------------------------------------------------------------------------
__global__ __launch_bounds__(256) void prep(
    const float* __restrict__ x, const float* __restrict__ context,
    const float* __restrict__ Wq, const float* __restrict__ Wk,
    const float* __restrict__ Wv1, const float* __restrict__ Wout,
    ushort_t* __restrict__ x_b, ushort_t* __restrict__ ctx_b,
    ushort_t* __restrict__ Wq_t, ushort_t* __restrict__ Wk_t,
    ushort_t* __restrict__ Wv1_t, ushort_t* __restrict__ Wout_b,
    float* __restrict__ colzero,   // colsum|colsumsq, 2*Mn floats
    int b, int n) {
    const int t = threadIdx.x;
    const int bid = blockIdx.x;
    const int nb_x = (b * 64 * 768 / 4) / 256;
    const int nb_c = (b * n * 768 / 4) / 256;

    if (bid < nb_x + nb_c) {  // flat converts (x, context)
        const float* in = (bid < nb_x) ? x : context;
        ushort_t* outp = (bid < nb_x) ? x_b : ctx_b;
        const int i = ((bid < nb_x) ? bid : (bid - nb_x)) * 256 + t;
        float4 v = ((const float4*)in)[i];
        ushort_t o[4] = {f2b_rne(v.x), f2b_rne(v.y), f2b_rne(v.z), f2b_rne(v.w)};
        *(uint2*)&outp[(size_t)i * 4] = *(uint2*)o;
        return;
    }

    int u = bid - nb_x - nb_c;
    if (u >= 4800) {  // zero colsum/colsumsq: 8 blocks x 256 x float4
        const int idx = (u - 4800) * 256 + t;
        ((float4*)colzero)[idx] = make_float4(0.f, 0.f, 0.f, 0.f);
        return;
    }
    if (u >= 4224) {  // Wout flat convert: 576 blocks x 1024 floats
        const int i = (u - 4224) * 256 + t;
        float4 v = ((const float4*)Wout)[i];
        ushort_t o[4] = {f2b_rne(v.x), f2b_rne(v.y), f2b_rne(v.z), f2b_rne(v.w)};
        *(uint2*)&Wout_b[(size_t)i * 4] = *(uint2*)o;
        return;
    }

    // transposes: Wq 576, Wk 576, Wv1 3072
    const float* in;
    ushort_t* outp;
    int R = 768, C = 768;
    if (u < 576)        { in = Wq;  outp = Wq_t; }
    else if (u < 1152)  { u -= 576;  in = Wk;  outp = Wk_t; }
    else                { u -= 1152; in = Wv1; outp = Wv1_t; C = 4096; }
    const int ct = C / 32;
    const int c0 = (u % ct) * 32, r0 = (u / ct) * 32;
    const int tx = t & 31, ty = t >> 5;

    __shared__ float tt[32][33];
#pragma unroll
    for (int i = 0; i < 4; i++)
        tt[ty + 8 * i][tx] = in[(size_t)(r0 + ty + 8 * i) * C + c0 + tx];
    __syncthreads();
#pragma unroll
    for (int i = 0; i < 4; i++)
        outp[(size_t)(c0 + ty + 8 * i) * R + r0 + tx] = f2b_rne(tt[tx][ty + 8 * i]);
}

// ---------------------------------------------------------------------------
// gemm3: q, k GEMMs + h1^T GEMM (C[c][n_glob] = Wv1t @ ctx^T) via tile list.
// m97 global_load_lds staging. Clean epilogue (VGPR 72, ~23% occupancy).
// ---------------------------------------------------------------------------
__global__ __launch_bounds__(256) void gemm3(
    const ushort_t* __restrict__ x_b, const ushort_t* __restrict__ ctx_b,
    const ushort_t* __restrict__ Wq_t, const ushort_t* __restrict__ Wk_t,
    const ushort_t* __restrict__ Wv1_t,
    ushort_t* __restrict__ qb, ushort_t* __restrict__ kb,
    ushort_t* __restrict__ h1t, int b, int n) {
    const int bid = blockIdx.x;
    const int tq = (b * 64 / 128) * 6;
    const int tk = (b * n / 128) * 6;
    const int Mn = b * n;

    const ushort_t *A, *Bt;
    ushort_t* C;
    int N, row0, col0;
    if (bid < tq) {
        A = x_b; Bt = Wq_t; C = qb; N = 768;
        row0 = (bid / 6) * 128; col0 = (bid % 6) * 128;
    } else if (bid < tq + tk) {
        const int u = bid - tq;
        A = ctx_b; Bt = Wk_t; C = kb; N = 768;
        row0 = (u / 6) * 128; col0 = (u % 6) * 128;
    } else {
        const int u = bid - tq - tk;
        A = Wv1_t; Bt = ctx_b; C = h1t; N = Mn;
        row0 = (u % 32) * 128; col0 = (u / 32) * 128;
    }
    const int K = 768;

    __shared__ ushort_t As[128 * 32];
    __shared__ ushort_t Bs[128 * 32];

    const int t = threadIdx.x;
    const int lane = t & 63;
    const int wave = t >> 6;
    const int quad = lane >> 4;
    const int l15 = lane & 15;
    const int wm = (wave >> 1) * 64;
    const int wn = (wave & 1) * 64;

    const ushort_t* ga0 = A + (size_t)(row0 + (t >> 2)) * K + (t & 3) * 8;
    const ushort_t* ga1 = ga0 + (size_t)64 * K;
    const ushort_t* gb0 = Bt + (size_t)(col0 + (t >> 2)) * K + (t & 3) * 8;
    const ushort_t* gb1 = gb0 + (size_t)64 * K;

    ushort_t* lA0 = &As[wave * 512];
    ushort_t* lA1 = &As[2048 + wave * 512];
    ushort_t* lB0 = &Bs[wave * 512];
    ushort_t* lB1 = &Bs[2048 + wave * 512];

    f32x4 acc[4][4] = {};

    for (int k0 = 0; k0 < K; k0 += 32) {
        __syncthreads();
        gl_lds16(ga0 + k0, lA0);
        gl_lds16(ga1 + k0, lA1);
        gl_lds16(gb0 + k0, lB0);
        gl_lds16(gb1 + k0, lB1);
        __syncthreads();

        bf16x8 af[4], bfr[4];
#pragma unroll
        for (int i = 0; i < 4; i++)
            af[i] = *(const bf16x8*)&As[(wm + i * 16 + l15) * 32 + quad * 8];
#pragma unroll
        for (int j = 0; j < 4; j++)
            bfr[j] = *(const bf16x8*)&Bs[(wn + j * 16 + l15) * 32 + quad * 8];
#pragma unroll
        for (int i = 0; i < 4; i++)
#pragma unroll
            for (int j = 0; j < 4; j++)
                acc[i][j] = __builtin_amdgcn_mfma_f32_16x16x32_bf16(
                    af[i], bfr[j], acc[i][j], 0, 0, 0);
    }

#pragma unroll
    for (int i = 0; i < 4; i++)
#pragma unroll
        for (int j = 0; j < 4; j++)
#pragma unroll
            for (int r = 0; r < 4; r++) {
                const int row = row0 + wm + i * 16 + quad * 4 + r;
                const int col = col0 + wn + j * 16 + l15;
                C[(size_t)row * N + col] = f2b_rne(acc[i][j][r]);
            }
}

// ---------------------------------------------------------------------------
// scores_stats: region 0 (b*8*(n/128)): S = QK^T/sqrt(96).
// region 1 (256 blocks): LN col sums of h1t, 256x256 panels, bf16x8 loads.
// ---------------------------------------------------------------------------
__global__ __launch_bounds__(256) void scores_stats(
    const ushort_t* __restrict__ qb, const ushort_t* __restrict__ kb,
    const ushort_t* __restrict__ h1t, float* __restrict__ S,
    float* __restrict__ colsum, float* __restrict__ colsumsq,
    int b, int n, int Mn) {
    __shared__ ushort_t sb[192 * 104];
    const int t = threadIdx.x;
    const int nsc = b * 8 * (n / 128);

    if (blockIdx.x >= nsc) {  // ---- LN column-sum panel (256 rows x 256 cols) ----
        const int u = blockIdx.x - nsc;
        const int rc = u >> 4;
        const int cc = u & 15;
        const int cg = t & 31;
        const int rg = t >> 5;
        const ushort_t* p =
            h1t + (size_t)(rc * 256 + rg * 32) * Mn + cc * 256 + cg * 8;
        float s[8] = {}, s2[8] = {};
#pragma unroll 4
        for (int r = 0; r < 32; r++) {
            const bf16x8 v = *(const bf16x8*)&p[(size_t)r * Mn];
#pragma unroll
            for (int j = 0; j < 8; j++) {
                const float f = (float)v[j];
                s[j] += f;
                s2[j] += f * f;
            }
        }
        float* red = (float*)sb;
#pragma unroll
        for (int j = 0; j < 8; j++) {
            red[rg * 256 + cg * 8 + j] = s[j];
            red[2048 + rg * 256 + cg * 8 + j] = s2[j];
        }
        __syncthreads();
        float ts = 0.f, ts2 = 0.f;
#pragma unroll
        for (int g = 0; g < 8; g++) {
            ts += red[g * 256 + t];
            ts2 += red[2048 + g * 256 + t];
        }
        atomicAdd(&colsum[cc * 256 + t], ts);
        atomicAdd(&colsumsq[cc * 256 + t], ts2);
        return;
    }

    // ---- scores tile ----
    const int nt = n / 128;
    const int n0 = (blockIdx.x % nt) * 128;
    const int bh = blockIdx.x / nt;
    const int bb = bh >> 3, h = bh & 7;
    const int lane = t & 63, wave = t >> 6;
    const int quad = lane >> 4, l15 = lane & 15;
    const int wm = (wave >> 1) * 32;
    const int wn = (wave & 1) * 64;

    ushort_t* Qs = sb;
    ushort_t* Ks = sb + 64 * 104;

    for (int g = t; g < 768; g += 256) {
        const int r = g / 12, s = g - r * 12;
        *(bf16x8*)&Qs[r * 104 + s * 8] =
            *(const bf16x8*)&qb[(size_t)(bb * 64 + r) * 768 + h * 96 + s * 8];
    }
    for (int g = t; g < 1536; g += 256) {
        const int r = g / 12, s = g - r * 12;
        *(bf16x8*)&Ks[r * 104 + s * 8] =
            *(const bf16x8*)&kb[(size_t)(bb * n + n0 + r) * 768 + h * 96 + s * 8];
    }
    __syncthreads();

    f32x4 acc[2][4] = {};
#pragma unroll
    for (int ks = 0; ks < 3; ks++) {
        bf16x8 af[2], bfr[4];
#pragma unroll
        for (int i = 0; i < 2; i++)
            af[i] = *(const bf16x8*)&Qs[(wm + i * 16 + l15) * 104 + ks * 32 + quad * 8];
#pragma unroll
        for (int j = 0; j < 4; j++)
            bfr[j] = *(const bf16x8*)&Ks[(wn + j * 16 + l15) * 104 + ks * 32 + quad * 8];
#pragma unroll
        for (int i = 0; i < 2; i++)
#pragma unroll
            for (int j = 0; j < 4; j++)
                acc[i][j] = __builtin_amdgcn_mfma_f32_16x16x32_bf16(
                    af[i], bfr[j], acc[i][j], 0, 0, 0);
    }

    const float sc = 0.10206207261596575f;  // 1/sqrt(96)
    float* Sp = S + (size_t)bh * 64 * n;
#pragma unroll
    for (int i = 0; i < 2; i++)
#pragma unroll
        for (int j = 0; j < 4; j++)
#pragma unroll
            for (int r = 0; r < 4; r++) {
                const int row = wm + i * 16 + quad * 4 + r;
                const int col = n0 + wn + j * 16 + l15;
                Sp[(size_t)row * n + col] = acc[i][j][r] * sc;
            }
}

// ---------------------------------------------------------------------------
// attn_fused (1024 thr / 16 waves): one block per (b,qi).
// - softmax: 2 waves per head over half of n each; partials merged in LDS.
// - PV MFMA: waves 0..3 each own one 16-col j-block (no redundancy).
// - LN affine + Wc apply -> sO row (bf16-rounded) in LDS.
// - FUSED Wout matvec: dout = tid, sum over d: Wout_b[d*768+dout] coalesced
//   across lanes; sO[d] is same-address LDS broadcast (free). fp32 out.
// ---------------------------------------------------------------------------
__global__ __launch_bounds__(1024) void attn_fused(
    const float* __restrict__ S, const float* __restrict__ colsum,
    const float* __restrict__ colsumsq, const ushort_t* __restrict__ h1t,
    const float* __restrict__ ln_g, const float* __restrict__ ln_b,
    const float* __restrict__ Wc, const ushort_t* __restrict__ Wout_b,
    float* __restrict__ out, int n, int Mn) {
    const int bq = blockIdx.x;
    const int bb = bq >> 6, qi = bq & 63;
    const int tid = threadIdx.x;
    const int lane = tid & 63, wv = tid >> 6;   // wv 0..15
    const int quad = lane >> 4, l15 = lane & 15;

    __shared__ ushort_t sW[9 * 1032];   // rows 0..7 = w[h], row 8 = zeros
    __shared__ ushort_t sH[64 * 264];   // H chunk; overlay: mu/rstd before PV
    __shared__ float sl[8], swmu[8];
    __shared__ float pm[16], pl[16], pwm[16];
    __shared__ float sA[512];
    __shared__ float sO[768];           // Wc-applied row (bf16-rounded)

    float* sMu = (float*)sH;            // [1024] (overwritten by chunk 0 stage)
    float* sRs = (float*)sH + 1024;     // [1024]

    // LN stats from column sums
    for (int i = tid; i < n; i += 1024) {
        const float cs = colsum[bb * n + i];
        const float cq = colsumsq[bb * n + i];
        const float m = cs * (1.0f / 4096.0f);
        sMu[i] = m;
        sRs[i] = rsqrtf(cq * (1.0f / 4096.0f) - m * m + 1e-5f);
    }
    // zero row 8 of sW
    for (int i = tid; i < 1032; i += 1024) sW[8 * 1032 + i] = 0;
    __syncthreads();

    // softmax: head h = wv>>1; each wave handles half of n.
    const int h = wv >> 1;
    const int half = wv & 1;
    const int nh = n >> 1;
    const int i0 = half * nh;
    const float* Sp = S + ((size_t)(bb * 8 + h) * 64 + qi) * n;
    {
        float m = -1e30f;
        for (int i = i0 + lane; i < i0 + nh; i += 64) m = fmaxf(m, Sp[i]);
#pragma unroll
        for (int off = 32; off > 0; off >>= 1) m = fmaxf(m, __shfl_down(m, off));
        if (lane == 0) pm[wv] = m;
    }
    __syncthreads();
    const float mh = fmaxf(pm[2 * h], pm[2 * h + 1]);
    {
        float l = 0.f, wm = 0.f;
        for (int i = i0 + lane; i < i0 + nh; i += 64) {
            const float e = expf(Sp[i] - mh);
            const float w = e * sRs[i];
            const ushort_t wb = f2b_rne(w);
            sW[h * 1032 + i] = wb;
            l += e;
            wm += b2f(wb) * sMu[i];
        }
#pragma unroll
        for (int off = 32; off > 0; off >>= 1) {
            l += __shfl_down(l, off);
            wm += __shfl_down(wm, off);
        }
        if (lane == 0) { pl[wv] = l; pwm[wv] = wm; }
    }
    __syncthreads();
    if (tid < 8) {
        sl[tid] = pl[2 * tid] + pl[2 * tid + 1];
        swmu[tid] = pwm[2 * tid] + pwm[2 * tid + 1];
    }

    // PV via MFMA: C[h(16)][r(64)] = w @ H^T, K = n in 256-chunks.
    const int mrow = (l15 < 8 ? l15 : 8) * 1032;
    f32x4 acc = {};
    const int nch = n >> 8;
    for (int ch = 0; ch < nch; ch++) {
        __syncthreads();  // chunk0: also protects sMu/sRs overlay + sW writes
        for (int g = tid; g < 2048; g += 1024) {
            const int row = g >> 5, seg = g & 31;
            *(bf16x8*)&sH[row * 264 + seg * 8] =
                *(const bf16x8*)&h1t[(size_t)(qi * 64 + row) * Mn + bb * n +
                                     ch * 256 + seg * 8];
        }
        __syncthreads();
        if (wv < 4) {
#pragma unroll
            for (int ks = 0; ks < 8; ks++) {
                const bf16x8 af = *(const bf16x8*)&sW[mrow + ch * 256 + ks * 32 + quad * 8];
                const bf16x8 bf = *(const bf16x8*)&sH[(wv * 16 + l15) * 264 + ks * 32 + quad * 8];
                acc = __builtin_amdgcn_mfma_f32_16x16x32_bf16(af, bf, acc, 0, 0, 0);
            }
        }
    }
    __syncthreads();

    // epilogue: wave j=wv<4 holds cols wv*16+l15, rows quad*4+r.
    if (wv < 4) {
#pragma unroll
        for (int r = 0; r < 4; r++) {
            const int hh = quad * 4 + r;
            if (hh < 8) {
                const int rr = wv * 16 + l15;
                const int c = qi * 64 + rr;
                sA[hh * 64 + rr] =
                    ln_g[c] * ((acc[r] - swmu[hh]) / sl[hh]) + ln_b[c];
            }
        }
    }
    __syncthreads();

    // Wc apply -> sO (bf16-rounded, fp32 storage for broadcast reads)
    for (int d = tid; d < 768; d += 1024) {
        const int hh = d / 96;
        const float* wp = Wc + (size_t)qi * 49152 + d;
        float a = 0.f;
#pragma unroll
        for (int r = 0; r < 64; r++) a += sA[hh * 64 + r] * wp[(size_t)r * 768];
        sO[d] = b2f(f2b_rne(a));
    }
    __syncthreads();

    // Fused Wout matvec: out[bq][dout] = sum_d sO[d] * Wout_b[d][dout].
    // Coalesced W reads across lanes; sO via float4 broadcast.
    if (tid < 768) {
        const int dout = tid;
        const float4* sO4 = (const float4*)sO;
        float a0 = 0.f, a1 = 0.f, a2 = 0.f, a3 = 0.f;
#pragma unroll 4
        for (int d4 = 0; d4 < 192; d4++) {
            const float4 s4 = sO4[d4];
            const int d = d4 * 4;
            a0 += s4.x * b2f(Wout_b[(size_t)d * 768 + dout]);
            a1 += s4.y * b2f(Wout_b[(size_t)(d + 1) * 768 + dout]);
            a2 += s4.z * b2f(Wout_b[(size_t)(d + 2) * 768 + dout]);
            a3 += s4.w * b2f(Wout_b[(size_t)(d + 3) * 768 + dout]);
        }
        out[(size_t)bq * 768 + dout] = (a0 + a1) + (a2 + a3);
    }
}

// ---------------------------------------------------------------------------
extern "C" void kernel_launch(void* const* d_in, const int* in_sizes, int n_in,
                              void* d_out, int out_size, void* d_ws, size_t ws_size,
                              hipStream_t stream) {
    const float* x       = (const float*)d_in[0];
    const float* context = (const float*)d_in[1];
    const float* Wq      = (const float*)d_in[2];
    const float* Wk      = (const float*)d_in[3];
    const float* Wv1     = (const float*)d_in[4];
    const float* ln_g    = (const float*)d_in[5];
    const float* ln_b    = (const float*)d_in[6];
    const float* Wc      = (const float*)d_in[7];
    const float* Wout    = (const float*)d_in[8];
    float* out = (float*)d_out;

    const int b = in_sizes[0] / (64 * 768);
    const int n = in_sizes[1] / (b * 768);
    const int M  = b * 64;     // 256
    const int Mn = b * n;      // 4096

    float* ws = (float*)d_ws;
    size_t off = 0;
    float* S       = ws + off;  off += (size_t)b * 8 * 64 * n;
    float* colsum  = ws + off;  off += (size_t)Mn;
    float* colsumsq= ws + off;  off += (size_t)Mn;

    ushort_t* us = (ushort_t*)(ws + off);
    size_t uo = 0;
    ushort_t* x_b    = us + uo;  uo += (size_t)M * 768;
    ushort_t* ctx_b  = us + uo;  uo += (size_t)Mn * 768;
    ushort_t* qb     = us + uo;  uo += (size_t)M * 768;
    ushort_t* kb     = us + uo;  uo += (size_t)Mn * 768;
    ushort_t* h1t    = us + uo;  uo += (size_t)Mn * 4096;   // [c][n_glob]
    ushort_t* Wq_t   = us + uo;  uo += (size_t)768 * 768;
    ushort_t* Wk_t   = us + uo;  uo += (size_t)768 * 768;
    ushort_t* Wv1_t  = us + uo;  uo += (size_t)4096 * 768;
    ushort_t* Wout_b = us + uo;  uo += (size_t)768 * 768;

    // 1. conversions + zero LN accumulators
    const int nb_x = (M * 768 / 4) / 256;
    const int nb_c = (Mn * 768 / 4) / 256;
    prep<<<nb_x + nb_c + 4800 + 8, 256, 0, stream>>>(
        x, context, Wq, Wk, Wv1, Wout, x_b, ctx_b, Wq_t, Wk_t, Wv1_t, Wout_b,
        colsum, b, n);

    // 2. q, k, h1^T GEMMs
    const int tq = (M / 128) * 6, tk = (Mn / 128) * 6;
    const int th = (4096 / 128) * (Mn / 128);
    gemm3<<<tq + tk + th, 256, 0, stream>>>(x_b, ctx_b, Wq_t, Wk_t, Wv1_t,
                                            qb, kb, h1t, b, n);

    // 3. scores + LN column sums
    scores_stats<<<b * 8 * (n / 128) + 256, 256, 0, stream>>>(
        qb, kb, h1t, S, colsum, colsumsq, b, n, Mn);

    // 4. fused softmax + PV-MFMA + LN affine + Wc + Wout matvec
    attn_fused<<<M, 1024, 0, stream>>>(S, colsum, colsumsq, h1t, ln_g, ln_b,
                                       Wc, Wout_b, out, n, Mn);
}

// Round 16
// 178.630 us; speedup vs baseline: 2.8847x; 1.0431x over previous
//
#include <hip/hip_runtime.h>
#include <math.h>

typedef unsigned short ushort_t;
typedef __bf16 bf16x8 __attribute__((ext_vector_type(8)));
typedef float f32x4 __attribute__((ext_vector_type(4)));

// ---------------------------------------------------------------------------
// fp32 <-> bf16 helpers
// ---------------------------------------------------------------------------
__device__ __forceinline__ ushort_t f2b_rne(float f) {
    union { float f; unsigned int u; } c;
    c.f = f;
    unsigned int u = c.u;
    u += 0x7FFFu + ((u >> 16) & 1u);
    return (ushort_t)(u >> 16);
}
__device__ __forceinline__ float b2f(ushort_t v) {
    union { unsigned int u; float f; } c;
    c.u = ((unsigned int)v) << 16;
    return c.f;
}

// async global->LDS DMA, 16B per lane.
__device__ __forceinline__ void gl_lds16(const ushort_t* g, ushort_t* l) {
    __builtin_amdgcn_global_load_lds(
        (const __attribute__((address_space(1))) void*)g,
        (__attribute__((address_space(3))) void*)l, 16, 0, 0);
}

// ---------------------------------------------------------------------------
// prep: all bf16 conversions + zeroing of LN colsum accumulators.
// Wout flat-converted (no transpose): Wout_b[d][dout] for the fused matvec.
// ---------------------------------------------------------------------------
__global__ __launch_bounds__(256) void prep(
    const float* __restrict__ x, const float* __restrict__ context,
    const float* __restrict__ Wq, const float* __restrict__ Wk,
    const float* __restrict__ Wv1, const float* __restrict__ Wout,
    ushort_t* __restrict__ x_b, ushort_t* __restrict__ ctx_b,
    ushort_t* __restrict__ Wq_t, ushort_t* __restrict__ Wk_t,
    ushort_t* __restrict__ Wv1_t, ushort_t* __restrict__ Wout_b,
    float* __restrict__ colzero,   // colsum|colsumsq, 2*Mn floats
    int b, int n) {
    const int t = threadIdx.x;
    const int bid = blockIdx.x;
    const int nb_x = (b * 64 * 768 / 4) / 256;
    const int nb_c = (b * n * 768 / 4) / 256;

    if (bid < nb_x + nb_c) {  // flat converts (x, context)
        const float* in = (bid < nb_x) ? x : context;
        ushort_t* outp = (bid < nb_x) ? x_b : ctx_b;
        const int i = ((bid < nb_x) ? bid : (bid - nb_x)) * 256 + t;
        float4 v = ((const float4*)in)[i];
        ushort_t o[4] = {f2b_rne(v.x), f2b_rne(v.y), f2b_rne(v.z), f2b_rne(v.w)};
        *(uint2*)&outp[(size_t)i * 4] = *(uint2*)o;
        return;
    }

    int u = bid - nb_x - nb_c;
    if (u >= 4800) {  // zero colsum/colsumsq: 8 blocks x 256 x float4
        const int idx = (u - 4800) * 256 + t;
        ((float4*)colzero)[idx] = make_float4(0.f, 0.f, 0.f, 0.f);
        return;
    }
    if (u >= 4224) {  // Wout flat convert: 576 blocks x 1024 floats
        const int i = (u - 4224) * 256 + t;
        float4 v = ((const float4*)Wout)[i];
        ushort_t o[4] = {f2b_rne(v.x), f2b_rne(v.y), f2b_rne(v.z), f2b_rne(v.w)};
        *(uint2*)&Wout_b[(size_t)i * 4] = *(uint2*)o;
        return;
    }

    // transposes: Wq 576, Wk 576, Wv1 3072
    const float* in;
    ushort_t* outp;
    int R = 768, C = 768;
    if (u < 576)        { in = Wq;  outp = Wq_t; }
    else if (u < 1152)  { u -= 576;  in = Wk;  outp = Wk_t; }
    else                { u -= 1152; in = Wv1; outp = Wv1_t; C = 4096; }
    const int ct = C / 32;
    const int c0 = (u % ct) * 32, r0 = (u / ct) * 32;
    const int tx = t & 31, ty = t >> 5;

    __shared__ float tt[32][33];
#pragma unroll
    for (int i = 0; i < 4; i++)
        tt[ty + 8 * i][tx] = in[(size_t)(r0 + ty + 8 * i) * C + c0 + tx];
    __syncthreads();
#pragma unroll
    for (int i = 0; i < 4; i++)
        outp[(size_t)(c0 + ty + 8 * i) * R + r0 + tx] = f2b_rne(tt[tx][ty + 8 * i]);
}

// ---------------------------------------------------------------------------
// gemm3: q, k GEMMs + h1^T GEMM via tile list. BK=64 as TWO stacked 32-slabs
// (each slab keeps the proven unpadded [128][32] layout -> DMA-contiguous,
// same fragment bank pattern). 8 DMA instrs + 32 MFMA per barrier pair;
// K-iters 24 -> 12 (halves the per-iter vmcnt(0)+barrier drain).
// ---------------------------------------------------------------------------
__global__ __launch_bounds__(256) void gemm3(
    const ushort_t* __restrict__ x_b, const ushort_t* __restrict__ ctx_b,
    const ushort_t* __restrict__ Wq_t, const ushort_t* __restrict__ Wk_t,
    const ushort_t* __restrict__ Wv1_t,
    ushort_t* __restrict__ qb, ushort_t* __restrict__ kb,
    ushort_t* __restrict__ h1t, int b, int n) {
    const int bid = blockIdx.x;
    const int tq = (b * 64 / 128) * 6;
    const int tk = (b * n / 128) * 6;
    const int Mn = b * n;

    const ushort_t *A, *Bt;
    ushort_t* C;
    int N, row0, col0;
    if (bid < tq) {
        A = x_b; Bt = Wq_t; C = qb; N = 768;
        row0 = (bid / 6) * 128; col0 = (bid % 6) * 128;
    } else if (bid < tq + tk) {
        const int u = bid - tq;
        A = ctx_b; Bt = Wk_t; C = kb; N = 768;
        row0 = (u / 6) * 128; col0 = (u % 6) * 128;
    } else {
        const int u = bid - tq - tk;
        A = Wv1_t; Bt = ctx_b; C = h1t; N = Mn;
        row0 = (u % 32) * 128; col0 = (u / 32) * 128;
    }
    const int K = 768;

    __shared__ ushort_t As[2 * 128 * 32];   // slab0 | slab1 (16KB each)
    __shared__ ushort_t Bs[2 * 128 * 32];

    const int t = threadIdx.x;
    const int lane = t & 63;
    const int wave = t >> 6;
    const int quad = lane >> 4;
    const int l15 = lane & 15;
    const int wm = (wave >> 1) * 64;
    const int wn = (wave & 1) * 64;

    // DMA mapping: granule g=t covers row t>>2, seg t&3 (slab0, rows 0..63 via
    // j=0; +64 rows via j=1); slab1 = same rows, segs 4..7 (K offset +32).
    const ushort_t* gA0 = A + (size_t)(row0 + (t >> 2)) * K + (t & 3) * 8;
    const ushort_t* gA1 = gA0 + (size_t)64 * K;
    const ushort_t* gB0 = Bt + (size_t)(col0 + (t >> 2)) * K + (t & 3) * 8;
    const ushort_t* gB1 = gB0 + (size_t)64 * K;

    ushort_t* lA0 = &As[wave * 512];
    ushort_t* lA1 = &As[2048 + wave * 512];
    ushort_t* lA2 = &As[4096 + wave * 512];
    ushort_t* lA3 = &As[6144 + wave * 512];
    ushort_t* lB0 = &Bs[wave * 512];
    ushort_t* lB1 = &Bs[2048 + wave * 512];
    ushort_t* lB2 = &Bs[4096 + wave * 512];
    ushort_t* lB3 = &Bs[6144 + wave * 512];

    f32x4 acc[4][4] = {};

    for (int k0 = 0; k0 < K; k0 += 64) {
        __syncthreads();
        gl_lds16(gA0 + k0, lA0);
        gl_lds16(gA1 + k0, lA1);
        gl_lds16(gA0 + k0 + 32, lA2);
        gl_lds16(gA1 + k0 + 32, lA3);
        gl_lds16(gB0 + k0, lB0);
        gl_lds16(gB1 + k0, lB1);
        gl_lds16(gB0 + k0 + 32, lB2);
        gl_lds16(gB1 + k0 + 32, lB3);
        __syncthreads();

#pragma unroll
        for (int ks = 0; ks < 2; ks++) {
            bf16x8 af[4], bfr[4];
#pragma unroll
            for (int i = 0; i < 4; i++)
                af[i] = *(const bf16x8*)&As[ks * 4096 + (wm + i * 16 + l15) * 32 + quad * 8];
#pragma unroll
            for (int j = 0; j < 4; j++)
                bfr[j] = *(const bf16x8*)&Bs[ks * 4096 + (wn + j * 16 + l15) * 32 + quad * 8];
#pragma unroll
            for (int i = 0; i < 4; i++)
#pragma unroll
                for (int j = 0; j < 4; j++)
                    acc[i][j] = __builtin_amdgcn_mfma_f32_16x16x32_bf16(
                        af[i], bfr[j], acc[i][j], 0, 0, 0);
        }
    }

    // C/D layout: col = lane&15, row = quad*4 + reg   [m89/m91]
#pragma unroll
    for (int i = 0; i < 4; i++)
#pragma unroll
        for (int j = 0; j < 4; j++)
#pragma unroll
            for (int r = 0; r < 4; r++) {
                const int row = row0 + wm + i * 16 + quad * 4 + r;
                const int col = col0 + wn + j * 16 + l15;
                C[(size_t)row * N + col] = f2b_rne(acc[i][j][r]);
            }
}

// ---------------------------------------------------------------------------
// scores_stats: region 0 (b*8*(n/128)): S = QK^T/sqrt(96).
// region 1 (256 blocks): LN col sums of h1t, 256x256 panels, bf16x8 loads.
// ---------------------------------------------------------------------------
__global__ __launch_bounds__(256) void scores_stats(
    const ushort_t* __restrict__ qb, const ushort_t* __restrict__ kb,
    const ushort_t* __restrict__ h1t, float* __restrict__ S,
    float* __restrict__ colsum, float* __restrict__ colsumsq,
    int b, int n, int Mn) {
    __shared__ ushort_t sb[192 * 104];
    const int t = threadIdx.x;
    const int nsc = b * 8 * (n / 128);

    if (blockIdx.x >= nsc) {  // ---- LN column-sum panel (256 rows x 256 cols) ----
        const int u = blockIdx.x - nsc;
        const int rc = u >> 4;
        const int cc = u & 15;
        const int cg = t & 31;
        const int rg = t >> 5;
        const ushort_t* p =
            h1t + (size_t)(rc * 256 + rg * 32) * Mn + cc * 256 + cg * 8;
        float s[8] = {}, s2[8] = {};
#pragma unroll 4
        for (int r = 0; r < 32; r++) {
            const bf16x8 v = *(const bf16x8*)&p[(size_t)r * Mn];
#pragma unroll
            for (int j = 0; j < 8; j++) {
                const float f = (float)v[j];
                s[j] += f;
                s2[j] += f * f;
            }
        }
        float* red = (float*)sb;
#pragma unroll
        for (int j = 0; j < 8; j++) {
            red[rg * 256 + cg * 8 + j] = s[j];
            red[2048 + rg * 256 + cg * 8 + j] = s2[j];
        }
        __syncthreads();
        float ts = 0.f, ts2 = 0.f;
#pragma unroll
        for (int g = 0; g < 8; g++) {
            ts += red[g * 256 + t];
            ts2 += red[2048 + g * 256 + t];
        }
        atomicAdd(&colsum[cc * 256 + t], ts);
        atomicAdd(&colsumsq[cc * 256 + t], ts2);
        return;
    }

    // ---- scores tile ----
    const int nt = n / 128;
    const int n0 = (blockIdx.x % nt) * 128;
    const int bh = blockIdx.x / nt;
    const int bb = bh >> 3, h = bh & 7;
    const int lane = t & 63, wave = t >> 6;
    const int quad = lane >> 4, l15 = lane & 15;
    const int wm = (wave >> 1) * 32;
    const int wn = (wave & 1) * 64;

    ushort_t* Qs = sb;
    ushort_t* Ks = sb + 64 * 104;

    for (int g = t; g < 768; g += 256) {
        const int r = g / 12, s = g - r * 12;
        *(bf16x8*)&Qs[r * 104 + s * 8] =
            *(const bf16x8*)&qb[(size_t)(bb * 64 + r) * 768 + h * 96 + s * 8];
    }
    for (int g = t; g < 1536; g += 256) {
        const int r = g / 12, s = g - r * 12;
        *(bf16x8*)&Ks[r * 104 + s * 8] =
            *(const bf16x8*)&kb[(size_t)(bb * n + n0 + r) * 768 + h * 96 + s * 8];
    }
    __syncthreads();

    f32x4 acc[2][4] = {};
#pragma unroll
    for (int ks = 0; ks < 3; ks++) {
        bf16x8 af[2], bfr[4];
#pragma unroll
        for (int i = 0; i < 2; i++)
            af[i] = *(const bf16x8*)&Qs[(wm + i * 16 + l15) * 104 + ks * 32 + quad * 8];
#pragma unroll
        for (int j = 0; j < 4; j++)
            bfr[j] = *(const bf16x8*)&Ks[(wn + j * 16 + l15) * 104 + ks * 32 + quad * 8];
#pragma unroll
        for (int i = 0; i < 2; i++)
#pragma unroll
            for (int j = 0; j < 4; j++)
                acc[i][j] = __builtin_amdgcn_mfma_f32_16x16x32_bf16(
                    af[i], bfr[j], acc[i][j], 0, 0, 0);
    }

    const float sc = 0.10206207261596575f;  // 1/sqrt(96)
    float* Sp = S + (size_t)bh * 64 * n;
#pragma unroll
    for (int i = 0; i < 2; i++)
#pragma unroll
        for (int j = 0; j < 4; j++)
#pragma unroll
            for (int r = 0; r < 4; r++) {
                const int row = wm + i * 16 + quad * 4 + r;
                const int col = n0 + wn + j * 16 + l15;
                Sp[(size_t)row * n + col] = acc[i][j][r] * sc;
            }
}

// ---------------------------------------------------------------------------
// attn_fused (1024 thr / 16 waves): one block per (b,qi).
// - softmax: 2 waves per head over half of n each; partials merged in LDS.
// - PV MFMA: waves 0..3 each own one 16-col j-block (no redundancy).
// - LN affine + Wc apply -> sO row (bf16-rounded) in LDS.
// - Fused Wout matvec: dout = tid, Wout_b reads coalesced, sO broadcast.
// ---------------------------------------------------------------------------
__global__ __launch_bounds__(1024) void attn_fused(
    const float* __restrict__ S, const float* __restrict__ colsum,
    const float* __restrict__ colsumsq, const ushort_t* __restrict__ h1t,
    const float* __restrict__ ln_g, const float* __restrict__ ln_b,
    const float* __restrict__ Wc, const ushort_t* __restrict__ Wout_b,
    float* __restrict__ out, int n, int Mn) {
    const int bq = blockIdx.x;
    const int bb = bq >> 6, qi = bq & 63;
    const int tid = threadIdx.x;
    const int lane = tid & 63, wv = tid >> 6;   // wv 0..15
    const int quad = lane >> 4, l15 = lane & 15;

    __shared__ ushort_t sW[9 * 1032];   // rows 0..7 = w[h], row 8 = zeros
    __shared__ ushort_t sH[64 * 264];   // H chunk; overlay: mu/rstd before PV
    __shared__ float sl[8], swmu[8];
    __shared__ float pm[16], pl[16], pwm[16];
    __shared__ float sA[512];
    __shared__ float sO[768];           // Wc-applied row (bf16-rounded)

    float* sMu = (float*)sH;            // [1024] (overwritten by chunk 0 stage)
    float* sRs = (float*)sH + 1024;     // [1024]

    // LN stats from column sums
    for (int i = tid; i < n; i += 1024) {
        const float cs = colsum[bb * n + i];
        const float cq = colsumsq[bb * n + i];
        const float m = cs * (1.0f / 4096.0f);
        sMu[i] = m;
        sRs[i] = rsqrtf(cq * (1.0f / 4096.0f) - m * m + 1e-5f);
    }
    // zero row 8 of sW
    for (int i = tid; i < 1032; i += 1024) sW[8 * 1032 + i] = 0;
    __syncthreads();

    // softmax: head h = wv>>1; each wave handles half of n.
    const int h = wv >> 1;
    const int half = wv & 1;
    const int nh = n >> 1;
    const int i0 = half * nh;
    const float* Sp = S + ((size_t)(bb * 8 + h) * 64 + qi) * n;
    {
        float m = -1e30f;
        for (int i = i0 + lane; i < i0 + nh; i += 64) m = fmaxf(m, Sp[i]);
#pragma unroll
        for (int off = 32; off > 0; off >>= 1) m = fmaxf(m, __shfl_down(m, off));
        if (lane == 0) pm[wv] = m;
    }
    __syncthreads();
    const float mh = fmaxf(pm[2 * h], pm[2 * h + 1]);
    {
        float l = 0.f, wm = 0.f;
        for (int i = i0 + lane; i < i0 + nh; i += 64) {
            const float e = expf(Sp[i] - mh);
            const float w = e * sRs[i];
            const ushort_t wb = f2b_rne(w);
            sW[h * 1032 + i] = wb;
            l += e;
            wm += b2f(wb) * sMu[i];
        }
#pragma unroll
        for (int off = 32; off > 0; off >>= 1) {
            l += __shfl_down(l, off);
            wm += __shfl_down(wm, off);
        }
        if (lane == 0) { pl[wv] = l; pwm[wv] = wm; }
    }
    __syncthreads();
    if (tid < 8) {
        sl[tid] = pl[2 * tid] + pl[2 * tid + 1];
        swmu[tid] = pwm[2 * tid] + pwm[2 * tid + 1];
    }

    // PV via MFMA: C[h(16)][r(64)] = w @ H^T, K = n in 256-chunks.
    const int mrow = (l15 < 8 ? l15 : 8) * 1032;
    f32x4 acc = {};
    const int nch = n >> 8;
    for (int ch = 0; ch < nch; ch++) {
        __syncthreads();  // chunk0: also protects sMu/sRs overlay + sW writes
        for (int g = tid; g < 2048; g += 1024) {
            const int row = g >> 5, seg = g & 31;
            *(bf16x8*)&sH[row * 264 + seg * 8] =
                *(const bf16x8*)&h1t[(size_t)(qi * 64 + row) * Mn + bb * n +
                                     ch * 256 + seg * 8];
        }
        __syncthreads();
        if (wv < 4) {
#pragma unroll
            for (int ks = 0; ks < 8; ks++) {
                const bf16x8 af = *(const bf16x8*)&sW[mrow + ch * 256 + ks * 32 + quad * 8];
                const bf16x8 bf = *(const bf16x8*)&sH[(wv * 16 + l15) * 264 + ks * 32 + quad * 8];
                acc = __builtin_amdgcn_mfma_f32_16x16x32_bf16(af, bf, acc, 0, 0, 0);
            }
        }
    }
    __syncthreads();

    // epilogue: wave j=wv<4 holds cols wv*16+l15, rows quad*4+r.
    if (wv < 4) {
#pragma unroll
        for (int r = 0; r < 4; r++) {
            const int hh = quad * 4 + r;
            if (hh < 8) {
                const int rr = wv * 16 + l15;
                const int c = qi * 64 + rr;
                sA[hh * 64 + rr] =
                    ln_g[c] * ((acc[r] - swmu[hh]) / sl[hh]) + ln_b[c];
            }
        }
    }
    __syncthreads();

    // Wc apply -> sO (bf16-rounded, fp32 storage for broadcast reads)
    for (int d = tid; d < 768; d += 1024) {
        const int hh = d / 96;
        const float* wp = Wc + (size_t)qi * 49152 + d;
        float a = 0.f;
#pragma unroll
        for (int r = 0; r < 64; r++) a += sA[hh * 64 + r] * wp[(size_t)r * 768];
        sO[d] = b2f(f2b_rne(a));
    }
    __syncthreads();

    // Fused Wout matvec: out[bq][dout] = sum_d sO[d] * Wout_b[d][dout].
    if (tid < 768) {
        const int dout = tid;
        const float4* sO4 = (const float4*)sO;
        float a0 = 0.f, a1 = 0.f, a2 = 0.f, a3 = 0.f;
#pragma unroll 4
        for (int d4 = 0; d4 < 192; d4++) {
            const float4 s4 = sO4[d4];
            const int d = d4 * 4;
            a0 += s4.x * b2f(Wout_b[(size_t)d * 768 + dout]);
            a1 += s4.y * b2f(Wout_b[(size_t)(d + 1) * 768 + dout]);
            a2 += s4.z * b2f(Wout_b[(size_t)(d + 2) * 768 + dout]);
            a3 += s4.w * b2f(Wout_b[(size_t)(d + 3) * 768 + dout]);
        }
        out[(size_t)bq * 768 + dout] = (a0 + a1) + (a2 + a3);
    }
}

// ---------------------------------------------------------------------------
extern "C" void kernel_launch(void* const* d_in, const int* in_sizes, int n_in,
                              void* d_out, int out_size, void* d_ws, size_t ws_size,
                              hipStream_t stream) {
    const float* x       = (const float*)d_in[0];
    const float* context = (const float*)d_in[1];
    const float* Wq      = (const float*)d_in[2];
    const float* Wk      = (const float*)d_in[3];
    const float* Wv1     = (const float*)d_in[4];
    const float* ln_g    = (const float*)d_in[5];
    const float* ln_b    = (const float*)d_in[6];
    const float* Wc      = (const float*)d_in[7];
    const float* Wout    = (const float*)d_in[8];
    float* out = (float*)d_out;

    const int b = in_sizes[0] / (64 * 768);
    const int n = in_sizes[1] / (b * 768);
    const int M  = b * 64;     // 256
    const int Mn = b * n;      // 4096

    float* ws = (float*)d_ws;
    size_t off = 0;
    float* S       = ws + off;  off += (size_t)b * 8 * 64 * n;
    float* colsum  = ws + off;  off += (size_t)Mn;
    float* colsumsq= ws + off;  off += (size_t)Mn;

    ushort_t* us = (ushort_t*)(ws + off);
    size_t uo = 0;
    ushort_t* x_b    = us + uo;  uo += (size_t)M * 768;
    ushort_t* ctx_b  = us + uo;  uo += (size_t)Mn * 768;
    ushort_t* qb     = us + uo;  uo += (size_t)M * 768;
    ushort_t* kb     = us + uo;  uo += (size_t)Mn * 768;
    ushort_t* h1t    = us + uo;  uo += (size_t)Mn * 4096;   // [c][n_glob]
    ushort_t* Wq_t   = us + uo;  uo += (size_t)768 * 768;
    ushort_t* Wk_t   = us + uo;  uo += (size_t)768 * 768;
    ushort_t* Wv1_t  = us + uo;  uo += (size_t)4096 * 768;
    ushort_t* Wout_b = us + uo;  uo += (size_t)768 * 768;

    // 1. conversions + zero LN accumulators
    const int nb_x = (M * 768 / 4) / 256;
    const int nb_c = (Mn * 768 / 4) / 256;
    prep<<<nb_x + nb_c + 4800 + 8, 256, 0, stream>>>(
        x, context, Wq, Wk, Wv1, Wout, x_b, ctx_b, Wq_t, Wk_t, Wv1_t, Wout_b,
        colsum, b, n);

    // 2. q, k, h1^T GEMMs (BK=64, two stacked 32-slabs)
    const int tq = (M / 128) * 6, tk = (Mn / 128) * 6;
    const int th = (4096 / 128) * (Mn / 128);
    gemm3<<<tq + tk + th, 256, 0, stream>>>(x_b, ctx_b, Wq_t, Wk_t, Wv1_t,
                                            qb, kb, h1t, b, n);

    // 3. scores + LN column sums
    scores_stats<<<b * 8 * (n / 128) + 256, 256, 0, stream>>>(
        qb, kb, h1t, S, colsum, colsumsq, b, n, Mn);

    // 4. fused softmax + PV-MFMA + LN affine + Wc + Wout matvec
    attn_fused<<<M, 1024, 0, stream>>>(S, colsum, colsumsq, h1t, ln_g, ln_b,
                                       Wc, Wout_b, out, n, Mn);
}